// Round 9
// baseline (157.473 us; speedup 1.0000x reference)
//
#include <hip/hip_runtime.h>
#include <hip/hip_bf16.h>
#include <string.h>

// DeformableConv2d: B=4, C=256, O=256, H=W=64, K=3, pad=1, stride=1
// Round 19: K3 register-budget fix (one change vs r18: launch_bounds 512,2).
//   r18 post-mortem: f16 combine worked (VALUBusy 32->10.5, absmax 0.0039)
//   but dur rose 45->66.7us because the allocator, seeing less VALU work,
//   targeted 8-waves/EU and allocated only 64 VGPR (no spill, FETCH clean).
//   At 64 VGPR the pipeline state (gA,gB,ua,acc ~150 regs) can't stay live
//   -> loads serialized next to uses -> r13's software pipeline destroyed
//   (MfmaUtil 17->10.5). LDS still caps us at 1 block/CU (2 waves/EU), so
//   the heuristic's occupancy target was unreachable anyway. Fix: DEMAND
//   low occupancy -- __launch_bounds__(512, 2) raises the VGPR budget to
//   ~256 at zero occupancy cost (we are at 2 waves/EU regardless).
//   (r15's inverse lesson: never demand MORE occupancy than LDS allows;
//    here: never let the heuristic assume more than LDS allows either.)
// K0, K1, K2 byte-identical to round 18.
// Workspace: ws_off 1769472 | ws_b 1179648 | ws_a2 147456 | xt 8388608
//          = 11,485,184 B.

typedef __attribute__((ext_vector_type(8))) short short8;
typedef __attribute__((ext_vector_type(8))) _Float16 half8;
typedef __attribute__((ext_vector_type(2))) _Float16 half2v;
typedef __attribute__((ext_vector_type(16))) float floatx16;

__device__ __forceinline__ unsigned bfbits(float f) {
    unsigned u;
    __builtin_memcpy(&u, &f, 4);
    return (u + 0x7fffu + ((u >> 16) & 1u)) >> 16;   // RNE f32->bf16
}
__device__ __forceinline__ unsigned pack_bf16(float lo, float hi) {
    return bfbits(lo) | (bfbits(hi) << 16);
}
__device__ __forceinline__ unsigned pack_f16(float lo, float hi) {
    _Float16 a = (_Float16)lo, b = (_Float16)hi;
    unsigned short ua, ub;
    __builtin_memcpy(&ua, &a, 2);
    __builtin_memcpy(&ub, &b, 2);
    return (unsigned)ua | ((unsigned)ub << 16);
}

// async global->LDS DMA, 16 B per lane; lane l's data lands at lds + l*16.
__device__ __forceinline__ void gl_lds16(const void* g, void* l) {
    __builtin_amdgcn_global_load_lds(
        (const __attribute__((address_space(1))) unsigned int*)g,
        (__attribute__((address_space(3))) unsigned int*)l,
        16, 0, 0);
}

// ---------------------------------------------------------------------------
// K0: x (B,C,H,W) f32 -> xt (B,H,W,C) f16.  One block per (b, y) row.
// (verbatim rounds 12-18)
// ---------------------------------------------------------------------------
__global__ __launch_bounds__(256) void xpose_hwc_kernel(
    const float* __restrict__ x, unsigned short* __restrict__ xt)
{
    __shared__ float stage[256 * 65];
    const int bid = blockIdx.x;          // (b*64 + y)
    const int b = bid >> 6, y = bid & 63;
    const int tid = threadIdx.x;
    const float* src = x + (size_t)b * 256 * 4096 + y * 64;

#pragma unroll
    for (int i = 0; i < 16; ++i) {
        int idx = i * 256 + tid;         // 0..4095 = (c, xq)
        int c = idx >> 4, xq = idx & 15;
        float4 v = *(const float4*)&src[(size_t)c * 4096 + xq * 4];
        stage[c * 65 + xq * 4 + 0] = v.x;
        stage[c * 65 + xq * 4 + 1] = v.y;
        stage[c * 65 + xq * 4 + 2] = v.z;
        stage[c * 65 + xq * 4 + 3] = v.w;
    }
    __syncthreads();

    unsigned short* dst = xt + (size_t)bid * 16384;   // 64 px * 256 ch
#pragma unroll
    for (int i = 0; i < 32; ++i) {
        int c2 = (tid & 127) * 2;
        int xx = i * 2 + (tid >> 7);
        float f0 = stage[c2 * 65 + xx];
        float f1 = stage[(c2 + 1) * 65 + xx];
        *(unsigned*)&dst[xx * 256 + c2] = pack_f16(f0, f1);
    }
}

// ---------------------------------------------------------------------------
// K1: weight pack.  ws_b packed as f16 (consumed by K3's f16 MFMA);
// ws_a2 unchanged (f16, consumed by K2).  Otherwise verbatim rounds 4-18.
// ---------------------------------------------------------------------------
__global__ __launch_bounds__(256) void weight_pack_kernel(
    const float* __restrict__ w, const float* __restrict__ off_w,
    const float* __restrict__ mask_w,
    unsigned short* __restrict__ ws_b, unsigned short* __restrict__ ws_a2)
{
    __shared__ float slab[32 * 289];
    const int bid = blockIdx.x;
    const int tid = threadIdx.x;

    if (bid < 64) {
        const int nt = bid >> 3, cb = bid & 7;
        const float* wbase = w + (size_t)nt * 32 * 2304 + cb * 288;
#pragma unroll
        for (int i = 0; i < 9; ++i) {
            int idx = i * 256 + tid;               // 0..2303
            int o = idx / 72, f4 = idx % 72;
            float4 v = *(const float4*)&wbase[(size_t)o * 2304 + f4 * 4];
            slab[o * 289 + f4 * 4 + 0] = v.x;
            slab[o * 289 + f4 * 4 + 1] = v.y;
            slab[o * 289 + f4 * 4 + 2] = v.z;
            slab[o * 289 + f4 * 4 + 3] = v.w;
        }
        __syncthreads();
#pragma unroll
        for (int pass = 0; pass < 5; ++pass) {
            int rid = pass * 8 + (tid >> 5);
            if (rid < 36) {
                int kk = rid >> 2, q = rid & 3;
                int no = tid & 31;
                unsigned pk[4];
#pragma unroll
                for (int i = 0; i < 4; ++i) {
                    float f0 = slab[no * 289 + (q * 8 + 2 * i) * 9 + kk];
                    float f1 = slab[no * 289 + (q * 8 + 2 * i + 1) * 9 + kk];
                    pk[i] = pack_f16(f0, f1);          // f16 for K3's f16 MFMA
                }
                size_t u = ((size_t)nt * 288 + kk * 32 + cb * 4 + q) * 32 + no;
                *(uint4*)&ws_b[u * 8] = make_uint4(pk[0], pk[1], pk[2], pk[3]);
            }
        }
    } else {
        int e = (bid - 64) * 256 + tid;       // 0..9215
        int lan = e & 31;                     // oc row
        int ku = e >> 5;                      // 0..287
        int kk = ku >> 5;
        int c0 = (ku & 31) * 8;
        int o = lan;
        float f[8];
#pragma unroll
        for (int j = 0; j < 8; ++j) {
            int c = c0 + j;
            float v = 0.f;
            if (o < 18)      v = off_w[((size_t)o * 256 + c) * 9 + kk];
            else if (o < 27) v = mask_w[((size_t)(o - 18) * 256 + c) * 9 + kk];
            f[j] = v;
        }
        unsigned pk[4];
#pragma unroll
        for (int i = 0; i < 4; ++i) pk[i] = pack_f16(f[2 * i], f[2 * i + 1]);
        *(uint4*)&ws_a2[(size_t)e * 8] = make_uint4(pk[0], pk[1], pk[2], pk[3]);
    }
}

// ---------------------------------------------------------------------------
// K2: offset/mask conv, xt-direct edition (verbatim rounds 14-18).
// ---------------------------------------------------------------------------
__global__ __launch_bounds__(512) void offmask_mfma_kernel(
    const unsigned short* __restrict__ xt, const unsigned short* __restrict__ ws_a2,
    const float* __restrict__ off_b, const float* __restrict__ mask_b,
    float* __restrict__ ws_off)
{
    // [row r][p01 0..65][granule j 0..31] of 16B; logical kul at j = kul^(p01&7)
    __shared__ uint4 stage[3 * 66 * 32];      // 101,376 B; aliased as red[]
    const int bid = blockIdx.x;
    const int row = (bid & 7) * 32 + (bid >> 3);
    const int b = row >> 6, ho = row & 63;
    const int tid = threadIdx.x;
    const int l = tid & 63;
    const int w = tid >> 6;
    const int lan = l & 31, h = l >> 5;
    const int ntile = w >> 2, kq = w & 3;

    // ---- stage 3 input rows ----
    const char* xtb = (const char*)xt + (size_t)b * 64 * 32768;
    for (int r = 0; r < 3; ++r) {
        int y = ho - 1 + r;
        uint4* rowbase = &stage[r * 66 * 32];
        if (y >= 0 && y < 64) {
            const char* src = xtb + (size_t)y * 32768;
#pragma unroll
            for (int i = 0; i < 4; ++i) {
                int g0 = 32 + (w * 4 + i) * 64;
                int g = g0 + l;
                int p01 = g >> 5, j = g & 31;
                int kul = j ^ (p01 & 7);
                gl_lds16(src + ((size_t)(p01 - 1) * 32 + kul) * 16,
                         rowbase + g0);
            }
            if (tid < 64) {
                int g = (tid < 32) ? tid : (2080 + (tid - 32));
                rowbase[g] = make_uint4(0, 0, 0, 0);
            }
        } else {
            for (int g = tid; g < 2112; g += 512)
                rowbase[g] = make_uint4(0, 0, 0, 0);
        }
    }
    __syncthreads();                  // DMA drained; stage complete

    floatx16 acc;
#pragma unroll
    for (int r = 0; r < 16; ++r) acc[r] = 0.f;

    const uint4* a4 = (const uint4*)ws_a2;
    const int n = ntile * 32 + lan;   // output pixel for this lane
#pragma unroll
    for (int ky = 0; ky < 3; ++ky) {
#pragma unroll
        for (int kx = 0; kx < 3; ++kx) {
            int kk = ky * 3 + kx;
            int p01 = n + kx;
#pragma unroll
            for (int s4 = 0; s4 < 4; ++s4) {
                int s = kq * 4 + s4;          // K-step 0..15 within chunk
                int kul = s * 2 + h;          // local ku 0..31
                uint4 ua = a4[(size_t)(kk * 32 + kul) * 32 + lan];
                uint4 ub = stage[(ky * 66 + p01) * 32 + (kul ^ (p01 & 7))];
                half8 a, bb;
                __builtin_memcpy(&a, &ua, 16);
                __builtin_memcpy(&bb, &ub, 16);
                acc = __builtin_amdgcn_mfma_f32_32x32x16_f16(a, bb, acc, 0, 0, 0);
            }
        }
    }
    __syncthreads();                  // all waves done reading stage

    // cross-wave partial-C reduction (4 K-quarters per n-tile) - verbatim r9
    float* red = (float*)stage;       // 8 waves x 64 lanes x 16 = 32 KiB
#pragma unroll
    for (int r = 0; r < 16; ++r) red[(w * 64 + l) * 16 + r] = acc[r];
    __syncthreads();
    for (int idx = tid; idx < 27 * 64; idx += 512) {
        int oc = idx >> 6, wo = idx & 63;
        int nt2 = wo >> 5, nn = wo & 31;
        int h2 = (oc >> 2) & 1;
        int r = (oc & 3) | ((oc >> 3) << 2);
        int lane2 = nn + 32 * h2;
        float s = 0.f;
#pragma unroll
        for (int kq2 = 0; kq2 < 4; ++kq2)
            s += red[((nt2 * 4 + kq2) * 64 + lane2) * 16 + r];
        float v;
        if (oc < 18) {
            v = s + off_b[oc];
        } else {
            float t = s + mask_b[oc - 18];
            v = 1.f / (1.f + expf(-t));
        }
        ws_off[(size_t)row * 1728 + idx] = v;
    }
}

// ---------------------------------------------------------------------------
// K3: fused deformable sampling + GEMM, f16 packed-math edition.
// 256 blocks, 512 threads / 8 waves, 64 px/block, LDS 80384 B.
// __launch_bounds__(512, 2): LDS caps us at 1 block/CU = 2 waves/EU, so ask
// exactly that -> VGPR budget ~256 -> pipeline state stays in registers.
// ---------------------------------------------------------------------------
__global__ __launch_bounds__(512, 2) void deform_gemm_kernel(
    const unsigned short* __restrict__ xt, const float* __restrict__ ws_off,
    const unsigned short* __restrict__ ws_b, const float* __restrict__ bias,
    float* __restrict__ out)
{
    __shared__ uint4 paramw[576];       // per (tap,px): 4 dup-f16 corner weights
    __shared__ ushort4 paramo[576];     // per (tap,px): 4 clamped pixel indices
    __shared__ float biasl[256];
    __shared__ uint4 tile[2][2048];     // [buf][ku(32)*64 + n], XOR-swizzled, f16

    const int bid = blockIdx.x;
    const int row = (bid & 7) * 32 + (bid >> 3);
    const int b = row >> 6, ho = row & 63;
    const int tid = threadIdx.x;
    const int l = tid & 63;
    const int wid = tid >> 6;          // 0..7
    const int lan = l & 31;            // channel-group (producer) / MFMA lane
    const int h = l >> 5;              // pixel-parity (producer) / MFMA K-half

    if (tid < 256) biasl[tid] = bias[tid];

    // ---- per-(tap,pixel) sampling params: dup-f16 weights + corner indices
    {
        const float* ob = ws_off + (size_t)row * 1728;
        for (int it = tid; it < 576; it += 512) {
            int kk = it >> 6, p = it & 63;
            float dy = ob[(2 * kk) * 64 + p];
            float dx = ob[(2 * kk + 1) * 64 + p];
            float mk = ob[(18 + kk) * 64 + p];
            int ky = kk / 3, kx = kk - ky * 3;
            float py = (float)(ho - 1 + ky) + dy;
            float px = (float)(p - 1 + kx) + dx;
            float y0f = floorf(py), x0f = floorf(px);
            float wy1 = py - y0f, wx1 = px - x0f;
            float wy0 = 1.f - wy1, wx0 = 1.f - wx1;
            int y0 = (int)y0f, xi0 = (int)x0f;
            int y1 = y0 + 1, xi1 = xi0 + 1;
            float vy0 = (y0 >= 0 && y0 < 64) ? 1.f : 0.f;
            float vy1 = (y1 >= 0 && y1 < 64) ? 1.f : 0.f;
            float vx0 = (xi0 >= 0 && xi0 < 64) ? 1.f : 0.f;
            float vx1 = (xi1 >= 0 && xi1 < 64) ? 1.f : 0.f;
            float wr0 = wy0 * vy0 * mk, wr1 = wy1 * vy1 * mk;
            float wa = wx0 * vx0, wb2 = wx1 * vx1;
            int yc0 = min(max(y0, 0), 63), yc1 = min(max(y1, 0), 63);
            int xc0 = min(max(xi0, 0), 63), xc1 = min(max(xi1, 0), 63);
            float a00 = wr0 * wa, a01 = wr0 * wb2;
            float a10 = wr1 * wa, a11 = wr1 * wb2;
            paramw[it] = make_uint4(pack_f16(a00, a00), pack_f16(a01, a01),
                                    pack_f16(a10, a10), pack_f16(a11, a11));
            paramo[it] = make_ushort4((unsigned short)(yc0 * 64 + xc0),
                                      (unsigned short)(yc0 * 64 + xc1),
                                      (unsigned short)(yc1 * 64 + xc0),
                                      (unsigned short)(yc1 * 64 + xc1));
        }
    }
    __syncthreads();

    const char* xb16 = (const char*)xt + ((size_t)b << 21);   // b * 2 MiB
    const uint4* wb4 = (const uint4*)ws_b;

    floatx16 acc0, acc1;
#pragma unroll
    for (int r = 0; r < 16; ++r) { acc0[r] = 0.f; acc1[r] = 0.f; }

    // pipeline register state: 2-pixel gather half-batches
    uint4 gA[2][4], gB[2][4];
    uint4 wvA[2], wvB[2];
    uint4 ua[8];                        // reused for both K-batches

    auto issue_half = [&](int kk, int i0, uint4 (&g)[2][4], uint4 (&wv)[2]) {
#pragma unroll
        for (int i = 0; i < 2; ++i) {
            int p = wid * 8 + 2 * (i0 + i) + h;
            int e = kk * 64 + p;
            wv[i] = paramw[e];
            ushort4 uo = paramo[e];
            __builtin_memcpy(&g[i][0], xb16 + ((int)uo.x << 9) + (lan << 4), 16);
            __builtin_memcpy(&g[i][1], xb16 + ((int)uo.y << 9) + (lan << 4), 16);
            __builtin_memcpy(&g[i][2], xb16 + ((int)uo.z << 9) + (lan << 4), 16);
            __builtin_memcpy(&g[i][3], xb16 + ((int)uo.w << 9) + (lan << 4), 16);
        }
    };

    auto pack_half = [&](int buf, int i0, uint4 (&g)[2][4], uint4 (&wv)[2]) {
        char* tb = (char*)&tile[buf][0];
#pragma unroll
        for (int i = 0; i < 2; ++i) {
            int p = wid * 8 + 2 * (i0 + i) + h;
            half2v c00[4], c01[4], c10[4], c11[4], w00, w01, w10, w11;
            __builtin_memcpy(&c00, &g[i][0], 16);
            __builtin_memcpy(&c01, &g[i][1], 16);
            __builtin_memcpy(&c10, &g[i][2], 16);
            __builtin_memcpy(&c11, &g[i][3], 16);
            __builtin_memcpy(&w00, &wv[i].x, 4);
            __builtin_memcpy(&w01, &wv[i].y, 4);
            __builtin_memcpy(&w10, &wv[i].z, 4);
            __builtin_memcpy(&w11, &wv[i].w, 4);
            uint4 outv;
            unsigned* op = (unsigned*)&outv;
#pragma unroll
            for (int j = 0; j < 4; ++j) {
                half2v r = c00[j] * w00;          // v_pk_mul_f16
                r = c01[j] * w01 + r;             // v_pk_fma_f16
                r = c10[j] * w10 + r;
                r = c11[j] * w11 + r;
                __builtin_memcpy(&op[j], &r, 4);
            }
            __builtin_memcpy(tb + lan * 1024 + ((p << 4) ^ (lan << 4)), &outv, 16);
        }
    };

    // prologue: build tile[0] for tap 0
    issue_half(0, 0, gA, wvA);
    pack_half(0, 0, gA, wvA);
    issue_half(0, 2, gB, wvB);
    pack_half(0, 2, gB, wvB);
    __syncthreads();

    for (int kk = 0; kk < 9; ++kk) {
        const int buf = kk & 1, nbuf = (kk + 1) & 1;

        // vmcnt order per tap: U1, gA, U2, gB.
#pragma unroll
        for (int ks = 0; ks < 8; ++ks) {
            int kul = ks * 2 + h;
            ua[ks] = wb4[((size_t)wid * 288 + kk * 32 + kul) * 32 + lan];
        }
        if (kk < 8) issue_half(kk + 1, 0, gA, wvA);

        {   // MFMA ks 0..7 (waits U1; gA stays in flight)
            const char* tb = (const char*)&tile[buf][0];
#pragma unroll
            for (int ks = 0; ks < 8; ++ks) {
                int kul = ks * 2 + h;
                uint4 ub0, ub1;
                __builtin_memcpy(&ub0, tb + kul * 1024 + ((lan << 4) ^ (kul << 4)), 16);
                __builtin_memcpy(&ub1, tb + kul * 1024 + (((32 + lan) << 4) ^ (kul << 4)), 16);
                half8 a, b0, b1;
                __builtin_memcpy(&a, &ua[ks], 16);
                __builtin_memcpy(&b0, &ub0, 16);
                __builtin_memcpy(&b1, &ub1, 16);
                acc0 = __builtin_amdgcn_mfma_f32_32x32x16_f16(a, b0, acc0, 0, 0, 0);
                acc1 = __builtin_amdgcn_mfma_f32_32x32x16_f16(a, b1, acc1, 0, 0, 0);
            }
        }

        // ua batch 2 (ks 8..15) into the same registers (batch 1 consumed)
#pragma unroll
        for (int ks = 0; ks < 8; ++ks) {
            int kul = (ks + 8) * 2 + h;
            ua[ks] = wb4[((size_t)wid * 288 + kk * 32 + kul) * 32 + lan];
        }

        if (kk < 8) {
            pack_half(nbuf, 0, gA, wvA);     // waits gA; U2 stays in flight
            issue_half(kk + 1, 2, gB, wvB);
        }

        {   // MFMA ks 8..15 (waits U2; gB stays in flight)
            const char* tb = (const char*)&tile[buf][0];
#pragma unroll
            for (int ks = 0; ks < 8; ++ks) {
                int kul = (ks + 8) * 2 + h;
                uint4 ub0, ub1;
                __builtin_memcpy(&ub0, tb + kul * 1024 + ((lan << 4) ^ (kul << 4)), 16);
                __builtin_memcpy(&ub1, tb + kul * 1024 + (((32 + lan) << 4) ^ (kul << 4)), 16);
                half8 a, b0, b1;
                __builtin_memcpy(&a, &ua[ks], 16);
                __builtin_memcpy(&b0, &ub0, 16);
                __builtin_memcpy(&b1, &ub1, 16);
                acc0 = __builtin_amdgcn_mfma_f32_32x32x16_f16(a, b0, acc0, 0, 0, 0);
                acc1 = __builtin_amdgcn_mfma_f32_32x32x16_f16(a, b1, acc1, 0, 0, 0);
            }
        }

        if (kk < 8) pack_half(nbuf, 2, gB, wvB);
        __syncthreads();
    }

    // epilogue: wave wid owns m-tile wid, 2 n-tiles (verbatim)
#pragma unroll
    for (int nt = 0; nt < 2; ++nt) {
#pragma unroll
        for (int r = 0; r < 16; ++r) {
            int o = wid * 32 + (r & 3) + 8 * (r >> 2) + 4 * h;
            int woo = nt * 32 + lan;
            float v = (nt == 0) ? acc0[r] : acc1[r];
            out[(((size_t)b * 256 + o) * 64 + ho) * 64 + woo] = v + biasl[o];
        }
    }
}

extern "C" void kernel_launch(void* const* d_in, const int* in_sizes, int n_in,
                              void* d_out, int out_size, void* d_ws, size_t ws_size,
                              hipStream_t stream) {
    const float* x      = (const float*)d_in[0];
    const float* weight = (const float*)d_in[1];
    const float* bias   = (const float*)d_in[2];
    const float* off_w  = (const float*)d_in[3];
    const float* off_b  = (const float*)d_in[4];
    const float* mask_w = (const float*)d_in[5];
    const float* mask_b = (const float*)d_in[6];
    float* out = (float*)d_out;

    float* ws_off = (float*)d_ws;                                      // 1,769,472 B
    unsigned short* ws_b  = (unsigned short*)((char*)d_ws + 1769472);  // 1,179,648 B
    unsigned short* ws_a2 = (unsigned short*)((char*)d_ws + 2949120);  //   147,456 B
    unsigned short* xt    = (unsigned short*)((char*)d_ws + 3096576);  // 8,388,608 B

    hipLaunchKernelGGL(weight_pack_kernel, dim3(100), dim3(256), 0, stream,
                       weight, off_w, mask_w, ws_b, ws_a2);
    hipLaunchKernelGGL(xpose_hwc_kernel, dim3(256), dim3(256), 0, stream,
                       x, xt);
    hipLaunchKernelGGL(offmask_mfma_kernel, dim3(256), dim3(512), 0, stream,
                       xt, ws_a2, off_b, mask_b, ws_off);
    hipLaunchKernelGGL(deform_gemm_kernel, dim3(256), dim3(512), 0, stream,
                       xt, ws_off, ws_b, bias, out);
}

// Round 10
// 124.887 us; speedup vs baseline: 1.2609x; 1.2609x over previous
//
#include <hip/hip_runtime.h>
#include <hip/hip_bf16.h>
#include <string.h>

// DeformableConv2d: B=4, C=256, O=256, H=W=64, K=3, pad=1, stride=1
// Round 20: K3 sched_barrier phase pinning (one change vs r19).
//   r19 post-mortem: launch_bounds(512,2) raised the VGPR *cap* but the
//   machine scheduler still sank every gather load to sit directly before
//   its consumer (pressure heuristic; the f16 pack is too cheap to hold
//   the hoisted order that r16's bulky f32 pack preserved). VGPR stayed 64,
//   pipeline dead, dur 66.6us, MfmaUtil 10.5%. Fix: pin the phase order
//   with __builtin_amdgcn_sched_barrier(0) after each issue-cluster and
//   each MFMA cluster: {ua1+gA} | SB | {MFMA 0-7} | SB | {ua2, packA,
//   issue gB} | SB | {MFMA 8-15} | SB | {packB}. Loads can't sink past
//   the pin -> results stay live across MFMA -> in-flight pipeline
//   restored (VGPR should jump to ~130-190). Arithmetic untouched ->
//   absmax stays 0.00390625.
// K0, K1, K2 byte-identical to rounds 18-19.
// Workspace: ws_off 1769472 | ws_b 1179648 | ws_a2 147456 | xt 8388608
//          = 11,485,184 B.

typedef __attribute__((ext_vector_type(8))) short short8;
typedef __attribute__((ext_vector_type(8))) _Float16 half8;
typedef __attribute__((ext_vector_type(2))) _Float16 half2v;
typedef __attribute__((ext_vector_type(16))) float floatx16;

__device__ __forceinline__ unsigned bfbits(float f) {
    unsigned u;
    __builtin_memcpy(&u, &f, 4);
    return (u + 0x7fffu + ((u >> 16) & 1u)) >> 16;   // RNE f32->bf16
}
__device__ __forceinline__ unsigned pack_bf16(float lo, float hi) {
    return bfbits(lo) | (bfbits(hi) << 16);
}
__device__ __forceinline__ unsigned pack_f16(float lo, float hi) {
    _Float16 a = (_Float16)lo, b = (_Float16)hi;
    unsigned short ua, ub;
    __builtin_memcpy(&ua, &a, 2);
    __builtin_memcpy(&ub, &b, 2);
    return (unsigned)ua | ((unsigned)ub << 16);
}

// async global->LDS DMA, 16 B per lane; lane l's data lands at lds + l*16.
__device__ __forceinline__ void gl_lds16(const void* g, void* l) {
    __builtin_amdgcn_global_load_lds(
        (const __attribute__((address_space(1))) unsigned int*)g,
        (__attribute__((address_space(3))) unsigned int*)l,
        16, 0, 0);
}

// ---------------------------------------------------------------------------
// K0: x (B,C,H,W) f32 -> xt (B,H,W,C) f16.  One block per (b, y) row.
// (verbatim rounds 12-19)
// ---------------------------------------------------------------------------
__global__ __launch_bounds__(256) void xpose_hwc_kernel(
    const float* __restrict__ x, unsigned short* __restrict__ xt)
{
    __shared__ float stage[256 * 65];
    const int bid = blockIdx.x;          // (b*64 + y)
    const int b = bid >> 6, y = bid & 63;
    const int tid = threadIdx.x;
    const float* src = x + (size_t)b * 256 * 4096 + y * 64;

#pragma unroll
    for (int i = 0; i < 16; ++i) {
        int idx = i * 256 + tid;         // 0..4095 = (c, xq)
        int c = idx >> 4, xq = idx & 15;
        float4 v = *(const float4*)&src[(size_t)c * 4096 + xq * 4];
        stage[c * 65 + xq * 4 + 0] = v.x;
        stage[c * 65 + xq * 4 + 1] = v.y;
        stage[c * 65 + xq * 4 + 2] = v.z;
        stage[c * 65 + xq * 4 + 3] = v.w;
    }
    __syncthreads();

    unsigned short* dst = xt + (size_t)bid * 16384;   // 64 px * 256 ch
#pragma unroll
    for (int i = 0; i < 32; ++i) {
        int c2 = (tid & 127) * 2;
        int xx = i * 2 + (tid >> 7);
        float f0 = stage[c2 * 65 + xx];
        float f1 = stage[(c2 + 1) * 65 + xx];
        *(unsigned*)&dst[xx * 256 + c2] = pack_f16(f0, f1);
    }
}

// ---------------------------------------------------------------------------
// K1: weight pack.  ws_b packed as f16 (consumed by K3's f16 MFMA);
// ws_a2 unchanged (f16, consumed by K2).  Otherwise verbatim rounds 4-19.
// ---------------------------------------------------------------------------
__global__ __launch_bounds__(256) void weight_pack_kernel(
    const float* __restrict__ w, const float* __restrict__ off_w,
    const float* __restrict__ mask_w,
    unsigned short* __restrict__ ws_b, unsigned short* __restrict__ ws_a2)
{
    __shared__ float slab[32 * 289];
    const int bid = blockIdx.x;
    const int tid = threadIdx.x;

    if (bid < 64) {
        const int nt = bid >> 3, cb = bid & 7;
        const float* wbase = w + (size_t)nt * 32 * 2304 + cb * 288;
#pragma unroll
        for (int i = 0; i < 9; ++i) {
            int idx = i * 256 + tid;               // 0..2303
            int o = idx / 72, f4 = idx % 72;
            float4 v = *(const float4*)&wbase[(size_t)o * 2304 + f4 * 4];
            slab[o * 289 + f4 * 4 + 0] = v.x;
            slab[o * 289 + f4 * 4 + 1] = v.y;
            slab[o * 289 + f4 * 4 + 2] = v.z;
            slab[o * 289 + f4 * 4 + 3] = v.w;
        }
        __syncthreads();
#pragma unroll
        for (int pass = 0; pass < 5; ++pass) {
            int rid = pass * 8 + (tid >> 5);
            if (rid < 36) {
                int kk = rid >> 2, q = rid & 3;
                int no = tid & 31;
                unsigned pk[4];
#pragma unroll
                for (int i = 0; i < 4; ++i) {
                    float f0 = slab[no * 289 + (q * 8 + 2 * i) * 9 + kk];
                    float f1 = slab[no * 289 + (q * 8 + 2 * i + 1) * 9 + kk];
                    pk[i] = pack_f16(f0, f1);          // f16 for K3's f16 MFMA
                }
                size_t u = ((size_t)nt * 288 + kk * 32 + cb * 4 + q) * 32 + no;
                *(uint4*)&ws_b[u * 8] = make_uint4(pk[0], pk[1], pk[2], pk[3]);
            }
        }
    } else {
        int e = (bid - 64) * 256 + tid;       // 0..9215
        int lan = e & 31;                     // oc row
        int ku = e >> 5;                      // 0..287
        int kk = ku >> 5;
        int c0 = (ku & 31) * 8;
        int o = lan;
        float f[8];
#pragma unroll
        for (int j = 0; j < 8; ++j) {
            int c = c0 + j;
            float v = 0.f;
            if (o < 18)      v = off_w[((size_t)o * 256 + c) * 9 + kk];
            else if (o < 27) v = mask_w[((size_t)(o - 18) * 256 + c) * 9 + kk];
            f[j] = v;
        }
        unsigned pk[4];
#pragma unroll
        for (int i = 0; i < 4; ++i) pk[i] = pack_f16(f[2 * i], f[2 * i + 1]);
        *(uint4*)&ws_a2[(size_t)e * 8] = make_uint4(pk[0], pk[1], pk[2], pk[3]);
    }
}

// ---------------------------------------------------------------------------
// K2: offset/mask conv, xt-direct edition (verbatim rounds 14-19).
// ---------------------------------------------------------------------------
__global__ __launch_bounds__(512) void offmask_mfma_kernel(
    const unsigned short* __restrict__ xt, const unsigned short* __restrict__ ws_a2,
    const float* __restrict__ off_b, const float* __restrict__ mask_b,
    float* __restrict__ ws_off)
{
    // [row r][p01 0..65][granule j 0..31] of 16B; logical kul at j = kul^(p01&7)
    __shared__ uint4 stage[3 * 66 * 32];      // 101,376 B; aliased as red[]
    const int bid = blockIdx.x;
    const int row = (bid & 7) * 32 + (bid >> 3);
    const int b = row >> 6, ho = row & 63;
    const int tid = threadIdx.x;
    const int l = tid & 63;
    const int w = tid >> 6;
    const int lan = l & 31, h = l >> 5;
    const int ntile = w >> 2, kq = w & 3;

    // ---- stage 3 input rows ----
    const char* xtb = (const char*)xt + (size_t)b * 64 * 32768;
    for (int r = 0; r < 3; ++r) {
        int y = ho - 1 + r;
        uint4* rowbase = &stage[r * 66 * 32];
        if (y >= 0 && y < 64) {
            const char* src = xtb + (size_t)y * 32768;
#pragma unroll
            for (int i = 0; i < 4; ++i) {
                int g0 = 32 + (w * 4 + i) * 64;
                int g = g0 + l;
                int p01 = g >> 5, j = g & 31;
                int kul = j ^ (p01 & 7);
                gl_lds16(src + ((size_t)(p01 - 1) * 32 + kul) * 16,
                         rowbase + g0);
            }
            if (tid < 64) {
                int g = (tid < 32) ? tid : (2080 + (tid - 32));
                rowbase[g] = make_uint4(0, 0, 0, 0);
            }
        } else {
            for (int g = tid; g < 2112; g += 512)
                rowbase[g] = make_uint4(0, 0, 0, 0);
        }
    }
    __syncthreads();                  // DMA drained; stage complete

    floatx16 acc;
#pragma unroll
    for (int r = 0; r < 16; ++r) acc[r] = 0.f;

    const uint4* a4 = (const uint4*)ws_a2;
    const int n = ntile * 32 + lan;   // output pixel for this lane
#pragma unroll
    for (int ky = 0; ky < 3; ++ky) {
#pragma unroll
        for (int kx = 0; kx < 3; ++kx) {
            int kk = ky * 3 + kx;
            int p01 = n + kx;
#pragma unroll
            for (int s4 = 0; s4 < 4; ++s4) {
                int s = kq * 4 + s4;          // K-step 0..15 within chunk
                int kul = s * 2 + h;          // local ku 0..31
                uint4 ua = a4[(size_t)(kk * 32 + kul) * 32 + lan];
                uint4 ub = stage[(ky * 66 + p01) * 32 + (kul ^ (p01 & 7))];
                half8 a, bb;
                __builtin_memcpy(&a, &ua, 16);
                __builtin_memcpy(&bb, &ub, 16);
                acc = __builtin_amdgcn_mfma_f32_32x32x16_f16(a, bb, acc, 0, 0, 0);
            }
        }
    }
    __syncthreads();                  // all waves done reading stage

    // cross-wave partial-C reduction (4 K-quarters per n-tile) - verbatim r9
    float* red = (float*)stage;       // 8 waves x 64 lanes x 16 = 32 KiB
#pragma unroll
    for (int r = 0; r < 16; ++r) red[(w * 64 + l) * 16 + r] = acc[r];
    __syncthreads();
    for (int idx = tid; idx < 27 * 64; idx += 512) {
        int oc = idx >> 6, wo = idx & 63;
        int nt2 = wo >> 5, nn = wo & 31;
        int h2 = (oc >> 2) & 1;
        int r = (oc & 3) | ((oc >> 3) << 2);
        int lane2 = nn + 32 * h2;
        float s = 0.f;
#pragma unroll
        for (int kq2 = 0; kq2 < 4; ++kq2)
            s += red[((nt2 * 4 + kq2) * 64 + lane2) * 16 + r];
        float v;
        if (oc < 18) {
            v = s + off_b[oc];
        } else {
            float t = s + mask_b[oc - 18];
            v = 1.f / (1.f + expf(-t));
        }
        ws_off[(size_t)row * 1728 + idx] = v;
    }
}

// ---------------------------------------------------------------------------
// K3: fused deformable sampling + GEMM, f16 packed-math, phase-pinned.
// 256 blocks, 512 threads / 8 waves, 64 px/block, LDS 80384 B.
// sched_barrier(0) pins: {ua1+gA} | {MFMA 0-7} | {ua2,packA,gB} |
// {MFMA 8-15} | {packB}.  launch_bounds(512,2) grants the register budget.
// ---------------------------------------------------------------------------
__global__ __launch_bounds__(512, 2) void deform_gemm_kernel(
    const unsigned short* __restrict__ xt, const float* __restrict__ ws_off,
    const unsigned short* __restrict__ ws_b, const float* __restrict__ bias,
    float* __restrict__ out)
{
    __shared__ uint4 paramw[576];       // per (tap,px): 4 dup-f16 corner weights
    __shared__ ushort4 paramo[576];     // per (tap,px): 4 clamped pixel indices
    __shared__ float biasl[256];
    __shared__ uint4 tile[2][2048];     // [buf][ku(32)*64 + n], XOR-swizzled, f16

    const int bid = blockIdx.x;
    const int row = (bid & 7) * 32 + (bid >> 3);
    const int b = row >> 6, ho = row & 63;
    const int tid = threadIdx.x;
    const int l = tid & 63;
    const int wid = tid >> 6;          // 0..7
    const int lan = l & 31;            // channel-group (producer) / MFMA lane
    const int h = l >> 5;              // pixel-parity (producer) / MFMA K-half

    if (tid < 256) biasl[tid] = bias[tid];

    // ---- per-(tap,pixel) sampling params: dup-f16 weights + corner indices
    {
        const float* ob = ws_off + (size_t)row * 1728;
        for (int it = tid; it < 576; it += 512) {
            int kk = it >> 6, p = it & 63;
            float dy = ob[(2 * kk) * 64 + p];
            float dx = ob[(2 * kk + 1) * 64 + p];
            float mk = ob[(18 + kk) * 64 + p];
            int ky = kk / 3, kx = kk - ky * 3;
            float py = (float)(ho - 1 + ky) + dy;
            float px = (float)(p - 1 + kx) + dx;
            float y0f = floorf(py), x0f = floorf(px);
            float wy1 = py - y0f, wx1 = px - x0f;
            float wy0 = 1.f - wy1, wx0 = 1.f - wx1;
            int y0 = (int)y0f, xi0 = (int)x0f;
            int y1 = y0 + 1, xi1 = xi0 + 1;
            float vy0 = (y0 >= 0 && y0 < 64) ? 1.f : 0.f;
            float vy1 = (y1 >= 0 && y1 < 64) ? 1.f : 0.f;
            float vx0 = (xi0 >= 0 && xi0 < 64) ? 1.f : 0.f;
            float vx1 = (xi1 >= 0 && xi1 < 64) ? 1.f : 0.f;
            float wr0 = wy0 * vy0 * mk, wr1 = wy1 * vy1 * mk;
            float wa = wx0 * vx0, wb2 = wx1 * vx1;
            int yc0 = min(max(y0, 0), 63), yc1 = min(max(y1, 0), 63);
            int xc0 = min(max(xi0, 0), 63), xc1 = min(max(xi1, 0), 63);
            float a00 = wr0 * wa, a01 = wr0 * wb2;
            float a10 = wr1 * wa, a11 = wr1 * wb2;
            paramw[it] = make_uint4(pack_f16(a00, a00), pack_f16(a01, a01),
                                    pack_f16(a10, a10), pack_f16(a11, a11));
            paramo[it] = make_ushort4((unsigned short)(yc0 * 64 + xc0),
                                      (unsigned short)(yc0 * 64 + xc1),
                                      (unsigned short)(yc1 * 64 + xc0),
                                      (unsigned short)(yc1 * 64 + xc1));
        }
    }
    __syncthreads();

    const char* xb16 = (const char*)xt + ((size_t)b << 21);   // b * 2 MiB
    const uint4* wb4 = (const uint4*)ws_b;

    floatx16 acc0, acc1;
#pragma unroll
    for (int r = 0; r < 16; ++r) { acc0[r] = 0.f; acc1[r] = 0.f; }

    // pipeline register state: 2-pixel gather half-batches
    uint4 gA[2][4], gB[2][4];
    uint4 wvA[2], wvB[2];
    uint4 ua[8];                        // reused for both K-batches

    auto issue_half = [&](int kk, int i0, uint4 (&g)[2][4], uint4 (&wv)[2]) {
#pragma unroll
        for (int i = 0; i < 2; ++i) {
            int p = wid * 8 + 2 * (i0 + i) + h;
            int e = kk * 64 + p;
            wv[i] = paramw[e];
            ushort4 uo = paramo[e];
            __builtin_memcpy(&g[i][0], xb16 + ((int)uo.x << 9) + (lan << 4), 16);
            __builtin_memcpy(&g[i][1], xb16 + ((int)uo.y << 9) + (lan << 4), 16);
            __builtin_memcpy(&g[i][2], xb16 + ((int)uo.z << 9) + (lan << 4), 16);
            __builtin_memcpy(&g[i][3], xb16 + ((int)uo.w << 9) + (lan << 4), 16);
        }
    };

    auto pack_half = [&](int buf, int i0, uint4 (&g)[2][4], uint4 (&wv)[2]) {
        char* tb = (char*)&tile[buf][0];
#pragma unroll
        for (int i = 0; i < 2; ++i) {
            int p = wid * 8 + 2 * (i0 + i) + h;
            half2v c00[4], c01[4], c10[4], c11[4], w00, w01, w10, w11;
            __builtin_memcpy(&c00, &g[i][0], 16);
            __builtin_memcpy(&c01, &g[i][1], 16);
            __builtin_memcpy(&c10, &g[i][2], 16);
            __builtin_memcpy(&c11, &g[i][3], 16);
            __builtin_memcpy(&w00, &wv[i].x, 4);
            __builtin_memcpy(&w01, &wv[i].y, 4);
            __builtin_memcpy(&w10, &wv[i].z, 4);
            __builtin_memcpy(&w11, &wv[i].w, 4);
            uint4 outv;
            unsigned* op = (unsigned*)&outv;
#pragma unroll
            for (int j = 0; j < 4; ++j) {
                half2v r = c00[j] * w00;          // v_pk_mul_f16
                r = c01[j] * w01 + r;             // v_pk_fma_f16
                r = c10[j] * w10 + r;
                r = c11[j] * w11 + r;
                __builtin_memcpy(&op[j], &r, 4);
            }
            __builtin_memcpy(tb + lan * 1024 + ((p << 4) ^ (lan << 4)), &outv, 16);
        }
    };

    // prologue: build tile[0] for tap 0
    issue_half(0, 0, gA, wvA);
    pack_half(0, 0, gA, wvA);
    issue_half(0, 2, gB, wvB);
    pack_half(0, 2, gB, wvB);
    __syncthreads();

    for (int kk = 0; kk < 9; ++kk) {
        const int buf = kk & 1, nbuf = (kk + 1) & 1;

        // phase 1: issue ua batch 1 + next tap's gather half A
#pragma unroll
        for (int ks = 0; ks < 8; ++ks) {
            int kul = ks * 2 + h;
            ua[ks] = wb4[((size_t)wid * 288 + kk * 32 + kul) * 32 + lan];
        }
        if (kk < 8) issue_half(kk + 1, 0, gA, wvA);
        __builtin_amdgcn_sched_barrier(0);   // pin: loads stay issued here

        {   // phase 2: MFMA ks 0..7 (waits ua1; gA stays in flight)
            const char* tb = (const char*)&tile[buf][0];
#pragma unroll
            for (int ks = 0; ks < 8; ++ks) {
                int kul = ks * 2 + h;
                uint4 ub0, ub1;
                __builtin_memcpy(&ub0, tb + kul * 1024 + ((lan << 4) ^ (kul << 4)), 16);
                __builtin_memcpy(&ub1, tb + kul * 1024 + (((32 + lan) << 4) ^ (kul << 4)), 16);
                half8 a, b0, b1;
                __builtin_memcpy(&a, &ua[ks], 16);
                __builtin_memcpy(&b0, &ub0, 16);
                __builtin_memcpy(&b1, &ub1, 16);
                acc0 = __builtin_amdgcn_mfma_f32_32x32x16_f16(a, b0, acc0, 0, 0, 0);
                acc1 = __builtin_amdgcn_mfma_f32_32x32x16_f16(a, b1, acc1, 0, 0, 0);
            }
        }
        __builtin_amdgcn_sched_barrier(0);

        // phase 3: ua batch 2 + consume gA + issue gB
#pragma unroll
        for (int ks = 0; ks < 8; ++ks) {
            int kul = (ks + 8) * 2 + h;
            ua[ks] = wb4[((size_t)wid * 288 + kk * 32 + kul) * 32 + lan];
        }
        if (kk < 8) {
            pack_half(nbuf, 0, gA, wvA);     // waits gA; ua2 stays in flight
            issue_half(kk + 1, 2, gB, wvB);
        }
        __builtin_amdgcn_sched_barrier(0);

        {   // phase 4: MFMA ks 8..15 (waits ua2; gB stays in flight)
            const char* tb = (const char*)&tile[buf][0];
#pragma unroll
            for (int ks = 0; ks < 8; ++ks) {
                int kul = (ks + 8) * 2 + h;
                uint4 ub0, ub1;
                __builtin_memcpy(&ub0, tb + kul * 1024 + ((lan << 4) ^ (kul << 4)), 16);
                __builtin_memcpy(&ub1, tb + kul * 1024 + (((32 + lan) << 4) ^ (kul << 4)), 16);
                half8 a, b0, b1;
                __builtin_memcpy(&a, &ua[ks], 16);
                __builtin_memcpy(&b0, &ub0, 16);
                __builtin_memcpy(&b1, &ub1, 16);
                acc0 = __builtin_amdgcn_mfma_f32_32x32x16_f16(a, b0, acc0, 0, 0, 0);
                acc1 = __builtin_amdgcn_mfma_f32_32x32x16_f16(a, b1, acc1, 0, 0, 0);
            }
        }
        __builtin_amdgcn_sched_barrier(0);

        // phase 5: consume gB
        if (kk < 8) pack_half(nbuf, 2, gB, wvB);
        __syncthreads();
    }

    // epilogue: wave wid owns m-tile wid, 2 n-tiles (verbatim)
#pragma unroll
    for (int nt = 0; nt < 2; ++nt) {
#pragma unroll
        for (int r = 0; r < 16; ++r) {
            int o = wid * 32 + (r & 3) + 8 * (r >> 2) + 4 * h;
            int woo = nt * 32 + lan;
            float v = (nt == 0) ? acc0[r] : acc1[r];
            out[(((size_t)b * 256 + o) * 64 + ho) * 64 + woo] = v + biasl[o];
        }
    }
}

extern "C" void kernel_launch(void* const* d_in, const int* in_sizes, int n_in,
                              void* d_out, int out_size, void* d_ws, size_t ws_size,
                              hipStream_t stream) {
    const float* x      = (const float*)d_in[0];
    const float* weight = (const float*)d_in[1];
    const float* bias   = (const float*)d_in[2];
    const float* off_w  = (const float*)d_in[3];
    const float* off_b  = (const float*)d_in[4];
    const float* mask_w = (const float*)d_in[5];
    const float* mask_b = (const float*)d_in[6];
    float* out = (float*)d_out;

    float* ws_off = (float*)d_ws;                                      // 1,769,472 B
    unsigned short* ws_b  = (unsigned short*)((char*)d_ws + 1769472);  // 1,179,648 B
    unsigned short* ws_a2 = (unsigned short*)((char*)d_ws + 2949120);  //   147,456 B
    unsigned short* xt    = (unsigned short*)((char*)d_ws + 3096576);  // 8,388,608 B

    hipLaunchKernelGGL(weight_pack_kernel, dim3(100), dim3(256), 0, stream,
                       weight, off_w, mask_w, ws_b, ws_a2);
    hipLaunchKernelGGL(xpose_hwc_kernel, dim3(256), dim3(256), 0, stream,
                       x, xt);
    hipLaunchKernelGGL(offmask_mfma_kernel, dim3(256), dim3(512), 0, stream,
                       xt, ws_a2, off_b, mask_b, ws_off);
    hipLaunchKernelGGL(deform_gemm_kernel, dim3(256), dim3(512), 0, stream,
                       xt, ws_off, ws_b, bias, out);
}

// Round 11
// 123.977 us; speedup vs baseline: 1.2702x; 1.0073x over previous
//
#include <hip/hip_runtime.h>
#include <hip/hip_bf16.h>
#include <string.h>

// DeformableConv2d: B=4, C=256, O=256, H=W=64, K=3, pad=1, stride=1
// Round 21: K3 ua double-buffer prefetch (one change vs r20).
//   r20 post-mortem: sched_barrier pin landed (K3 66.6 -> ~34us, total
//   124.9). Remaining K3 model: ~17us L2-BW floor (2.3 MB/block L2->CU) +
//   exposed ua latency (ua1 issued phase 1, consumed phase 2 ~300cy stall;
//   ua2 issued phase 3, consumed phase 4). Fix: uaA/uaB double-buffer one
//   phase ahead -- phase 2 consumes uaA loaded during the PREVIOUS tap's
//   phase 3; phase 1 issues uaB(kk,ks8-15) consumed in phase 4 after a
//   full MFMA+pack section. Both ua stalls vanish. ~210 VGPR live, inside
//   the (512,2) budget. Arithmetic untouched -> absmax 0.00390625.
//   If total doesn't move: K3 is at its L2-BW floor -> BN=128 restructure.
// K0, K1, K2 byte-identical to rounds 18-20.
// Workspace: ws_off 1769472 | ws_b 1179648 | ws_a2 147456 | xt 8388608
//          = 11,485,184 B.

typedef __attribute__((ext_vector_type(8))) short short8;
typedef __attribute__((ext_vector_type(8))) _Float16 half8;
typedef __attribute__((ext_vector_type(2))) _Float16 half2v;
typedef __attribute__((ext_vector_type(16))) float floatx16;

__device__ __forceinline__ unsigned bfbits(float f) {
    unsigned u;
    __builtin_memcpy(&u, &f, 4);
    return (u + 0x7fffu + ((u >> 16) & 1u)) >> 16;   // RNE f32->bf16
}
__device__ __forceinline__ unsigned pack_bf16(float lo, float hi) {
    return bfbits(lo) | (bfbits(hi) << 16);
}
__device__ __forceinline__ unsigned pack_f16(float lo, float hi) {
    _Float16 a = (_Float16)lo, b = (_Float16)hi;
    unsigned short ua, ub;
    __builtin_memcpy(&ua, &a, 2);
    __builtin_memcpy(&ub, &b, 2);
    return (unsigned)ua | ((unsigned)ub << 16);
}

// async global->LDS DMA, 16 B per lane; lane l's data lands at lds + l*16.
__device__ __forceinline__ void gl_lds16(const void* g, void* l) {
    __builtin_amdgcn_global_load_lds(
        (const __attribute__((address_space(1))) unsigned int*)g,
        (__attribute__((address_space(3))) unsigned int*)l,
        16, 0, 0);
}

// ---------------------------------------------------------------------------
// K0: x (B,C,H,W) f32 -> xt (B,H,W,C) f16.  One block per (b, y) row.
// (verbatim rounds 12-20)
// ---------------------------------------------------------------------------
__global__ __launch_bounds__(256) void xpose_hwc_kernel(
    const float* __restrict__ x, unsigned short* __restrict__ xt)
{
    __shared__ float stage[256 * 65];
    const int bid = blockIdx.x;          // (b*64 + y)
    const int b = bid >> 6, y = bid & 63;
    const int tid = threadIdx.x;
    const float* src = x + (size_t)b * 256 * 4096 + y * 64;

#pragma unroll
    for (int i = 0; i < 16; ++i) {
        int idx = i * 256 + tid;         // 0..4095 = (c, xq)
        int c = idx >> 4, xq = idx & 15;
        float4 v = *(const float4*)&src[(size_t)c * 4096 + xq * 4];
        stage[c * 65 + xq * 4 + 0] = v.x;
        stage[c * 65 + xq * 4 + 1] = v.y;
        stage[c * 65 + xq * 4 + 2] = v.z;
        stage[c * 65 + xq * 4 + 3] = v.w;
    }
    __syncthreads();

    unsigned short* dst = xt + (size_t)bid * 16384;   // 64 px * 256 ch
#pragma unroll
    for (int i = 0; i < 32; ++i) {
        int c2 = (tid & 127) * 2;
        int xx = i * 2 + (tid >> 7);
        float f0 = stage[c2 * 65 + xx];
        float f1 = stage[(c2 + 1) * 65 + xx];
        *(unsigned*)&dst[xx * 256 + c2] = pack_f16(f0, f1);
    }
}

// ---------------------------------------------------------------------------
// K1: weight pack.  ws_b packed as f16 (consumed by K3's f16 MFMA);
// ws_a2 unchanged (f16, consumed by K2).  Otherwise verbatim rounds 4-20.
// ---------------------------------------------------------------------------
__global__ __launch_bounds__(256) void weight_pack_kernel(
    const float* __restrict__ w, const float* __restrict__ off_w,
    const float* __restrict__ mask_w,
    unsigned short* __restrict__ ws_b, unsigned short* __restrict__ ws_a2)
{
    __shared__ float slab[32 * 289];
    const int bid = blockIdx.x;
    const int tid = threadIdx.x;

    if (bid < 64) {
        const int nt = bid >> 3, cb = bid & 7;
        const float* wbase = w + (size_t)nt * 32 * 2304 + cb * 288;
#pragma unroll
        for (int i = 0; i < 9; ++i) {
            int idx = i * 256 + tid;               // 0..2303
            int o = idx / 72, f4 = idx % 72;
            float4 v = *(const float4*)&wbase[(size_t)o * 2304 + f4 * 4];
            slab[o * 289 + f4 * 4 + 0] = v.x;
            slab[o * 289 + f4 * 4 + 1] = v.y;
            slab[o * 289 + f4 * 4 + 2] = v.z;
            slab[o * 289 + f4 * 4 + 3] = v.w;
        }
        __syncthreads();
#pragma unroll
        for (int pass = 0; pass < 5; ++pass) {
            int rid = pass * 8 + (tid >> 5);
            if (rid < 36) {
                int kk = rid >> 2, q = rid & 3;
                int no = tid & 31;
                unsigned pk[4];
#pragma unroll
                for (int i = 0; i < 4; ++i) {
                    float f0 = slab[no * 289 + (q * 8 + 2 * i) * 9 + kk];
                    float f1 = slab[no * 289 + (q * 8 + 2 * i + 1) * 9 + kk];
                    pk[i] = pack_f16(f0, f1);          // f16 for K3's f16 MFMA
                }
                size_t u = ((size_t)nt * 288 + kk * 32 + cb * 4 + q) * 32 + no;
                *(uint4*)&ws_b[u * 8] = make_uint4(pk[0], pk[1], pk[2], pk[3]);
            }
        }
    } else {
        int e = (bid - 64) * 256 + tid;       // 0..9215
        int lan = e & 31;                     // oc row
        int ku = e >> 5;                      // 0..287
        int kk = ku >> 5;
        int c0 = (ku & 31) * 8;
        int o = lan;
        float f[8];
#pragma unroll
        for (int j = 0; j < 8; ++j) {
            int c = c0 + j;
            float v = 0.f;
            if (o < 18)      v = off_w[((size_t)o * 256 + c) * 9 + kk];
            else if (o < 27) v = mask_w[((size_t)(o - 18) * 256 + c) * 9 + kk];
            f[j] = v;
        }
        unsigned pk[4];
#pragma unroll
        for (int i = 0; i < 4; ++i) pk[i] = pack_f16(f[2 * i], f[2 * i + 1]);
        *(uint4*)&ws_a2[(size_t)e * 8] = make_uint4(pk[0], pk[1], pk[2], pk[3]);
    }
}

// ---------------------------------------------------------------------------
// K2: offset/mask conv, xt-direct edition (verbatim rounds 14-20).
// ---------------------------------------------------------------------------
__global__ __launch_bounds__(512) void offmask_mfma_kernel(
    const unsigned short* __restrict__ xt, const unsigned short* __restrict__ ws_a2,
    const float* __restrict__ off_b, const float* __restrict__ mask_b,
    float* __restrict__ ws_off)
{
    // [row r][p01 0..65][granule j 0..31] of 16B; logical kul at j = kul^(p01&7)
    __shared__ uint4 stage[3 * 66 * 32];      // 101,376 B; aliased as red[]
    const int bid = blockIdx.x;
    const int row = (bid & 7) * 32 + (bid >> 3);
    const int b = row >> 6, ho = row & 63;
    const int tid = threadIdx.x;
    const int l = tid & 63;
    const int w = tid >> 6;
    const int lan = l & 31, h = l >> 5;
    const int ntile = w >> 2, kq = w & 3;

    // ---- stage 3 input rows ----
    const char* xtb = (const char*)xt + (size_t)b * 64 * 32768;
    for (int r = 0; r < 3; ++r) {
        int y = ho - 1 + r;
        uint4* rowbase = &stage[r * 66 * 32];
        if (y >= 0 && y < 64) {
            const char* src = xtb + (size_t)y * 32768;
#pragma unroll
            for (int i = 0; i < 4; ++i) {
                int g0 = 32 + (w * 4 + i) * 64;
                int g = g0 + l;
                int p01 = g >> 5, j = g & 31;
                int kul = j ^ (p01 & 7);
                gl_lds16(src + ((size_t)(p01 - 1) * 32 + kul) * 16,
                         rowbase + g0);
            }
            if (tid < 64) {
                int g = (tid < 32) ? tid : (2080 + (tid - 32));
                rowbase[g] = make_uint4(0, 0, 0, 0);
            }
        } else {
            for (int g = tid; g < 2112; g += 512)
                rowbase[g] = make_uint4(0, 0, 0, 0);
        }
    }
    __syncthreads();                  // DMA drained; stage complete

    floatx16 acc;
#pragma unroll
    for (int r = 0; r < 16; ++r) acc[r] = 0.f;

    const uint4* a4 = (const uint4*)ws_a2;
    const int n = ntile * 32 + lan;   // output pixel for this lane
#pragma unroll
    for (int ky = 0; ky < 3; ++ky) {
#pragma unroll
        for (int kx = 0; kx < 3; ++kx) {
            int kk = ky * 3 + kx;
            int p01 = n + kx;
#pragma unroll
            for (int s4 = 0; s4 < 4; ++s4) {
                int s = kq * 4 + s4;          // K-step 0..15 within chunk
                int kul = s * 2 + h;          // local ku 0..31
                uint4 ua = a4[(size_t)(kk * 32 + kul) * 32 + lan];
                uint4 ub = stage[(ky * 66 + p01) * 32 + (kul ^ (p01 & 7))];
                half8 a, bb;
                __builtin_memcpy(&a, &ua, 16);
                __builtin_memcpy(&bb, &ub, 16);
                acc = __builtin_amdgcn_mfma_f32_32x32x16_f16(a, bb, acc, 0, 0, 0);
            }
        }
    }
    __syncthreads();                  // all waves done reading stage

    // cross-wave partial-C reduction (4 K-quarters per n-tile) - verbatim r9
    float* red = (float*)stage;       // 8 waves x 64 lanes x 16 = 32 KiB
#pragma unroll
    for (int r = 0; r < 16; ++r) red[(w * 64 + l) * 16 + r] = acc[r];
    __syncthreads();
    for (int idx = tid; idx < 27 * 64; idx += 512) {
        int oc = idx >> 6, wo = idx & 63;
        int nt2 = wo >> 5, nn = wo & 31;
        int h2 = (oc >> 2) & 1;
        int r = (oc & 3) | ((oc >> 3) << 2);
        int lane2 = nn + 32 * h2;
        float s = 0.f;
#pragma unroll
        for (int kq2 = 0; kq2 < 4; ++kq2)
            s += red[((nt2 * 4 + kq2) * 64 + lane2) * 16 + r];
        float v;
        if (oc < 18) {
            v = s + off_b[oc];
        } else {
            float t = s + mask_b[oc - 18];
            v = 1.f / (1.f + expf(-t));
        }
        ws_off[(size_t)row * 1728 + idx] = v;
    }
}

// ---------------------------------------------------------------------------
// K3: fused deformable sampling + GEMM, f16 packed-math, phase-pinned,
// ua double-buffered.  256 blocks, 512 threads / 8 waves, LDS 80384 B.
// Per tap: {uaB(kk,hi)+gA} | {MFMA 0-7 on uaA (in regs)} |
// {uaA(kk+1,lo), packA, gB} | {MFMA 8-15 on uaB} | {packB}.
// ---------------------------------------------------------------------------
__global__ __launch_bounds__(512, 2) void deform_gemm_kernel(
    const unsigned short* __restrict__ xt, const float* __restrict__ ws_off,
    const unsigned short* __restrict__ ws_b, const float* __restrict__ bias,
    float* __restrict__ out)
{
    __shared__ uint4 paramw[576];       // per (tap,px): 4 dup-f16 corner weights
    __shared__ ushort4 paramo[576];     // per (tap,px): 4 clamped pixel indices
    __shared__ float biasl[256];
    __shared__ uint4 tile[2][2048];     // [buf][ku(32)*64 + n], XOR-swizzled, f16

    const int bid = blockIdx.x;
    const int row = (bid & 7) * 32 + (bid >> 3);
    const int b = row >> 6, ho = row & 63;
    const int tid = threadIdx.x;
    const int l = tid & 63;
    const int wid = tid >> 6;          // 0..7
    const int lan = l & 31;            // channel-group (producer) / MFMA lane
    const int h = l >> 5;              // pixel-parity (producer) / MFMA K-half

    if (tid < 256) biasl[tid] = bias[tid];

    // ---- per-(tap,pixel) sampling params: dup-f16 weights + corner indices
    {
        const float* ob = ws_off + (size_t)row * 1728;
        for (int it = tid; it < 576; it += 512) {
            int kk = it >> 6, p = it & 63;
            float dy = ob[(2 * kk) * 64 + p];
            float dx = ob[(2 * kk + 1) * 64 + p];
            float mk = ob[(18 + kk) * 64 + p];
            int ky = kk / 3, kx = kk - ky * 3;
            float py = (float)(ho - 1 + ky) + dy;
            float px = (float)(p - 1 + kx) + dx;
            float y0f = floorf(py), x0f = floorf(px);
            float wy1 = py - y0f, wx1 = px - x0f;
            float wy0 = 1.f - wy1, wx0 = 1.f - wx1;
            int y0 = (int)y0f, xi0 = (int)x0f;
            int y1 = y0 + 1, xi1 = xi0 + 1;
            float vy0 = (y0 >= 0 && y0 < 64) ? 1.f : 0.f;
            float vy1 = (y1 >= 0 && y1 < 64) ? 1.f : 0.f;
            float vx0 = (xi0 >= 0 && xi0 < 64) ? 1.f : 0.f;
            float vx1 = (xi1 >= 0 && xi1 < 64) ? 1.f : 0.f;
            float wr0 = wy0 * vy0 * mk, wr1 = wy1 * vy1 * mk;
            float wa = wx0 * vx0, wb2 = wx1 * vx1;
            int yc0 = min(max(y0, 0), 63), yc1 = min(max(y1, 0), 63);
            int xc0 = min(max(xi0, 0), 63), xc1 = min(max(xi1, 0), 63);
            float a00 = wr0 * wa, a01 = wr0 * wb2;
            float a10 = wr1 * wa, a11 = wr1 * wb2;
            paramw[it] = make_uint4(pack_f16(a00, a00), pack_f16(a01, a01),
                                    pack_f16(a10, a10), pack_f16(a11, a11));
            paramo[it] = make_ushort4((unsigned short)(yc0 * 64 + xc0),
                                      (unsigned short)(yc0 * 64 + xc1),
                                      (unsigned short)(yc1 * 64 + xc0),
                                      (unsigned short)(yc1 * 64 + xc1));
        }
    }
    __syncthreads();

    const char* xb16 = (const char*)xt + ((size_t)b << 21);   // b * 2 MiB
    const uint4* wb4 = (const uint4*)ws_b;

    floatx16 acc0, acc1;
#pragma unroll
    for (int r = 0; r < 16; ++r) { acc0[r] = 0.f; acc1[r] = 0.f; }

    // pipeline register state: 2-pixel gather half-batches + ua double-buffer
    uint4 gA[2][4], gB[2][4];
    uint4 wvA[2], wvB[2];
    uint4 uaA[8], uaB[8];

    auto issue_half = [&](int kk, int i0, uint4 (&g)[2][4], uint4 (&wv)[2]) {
#pragma unroll
        for (int i = 0; i < 2; ++i) {
            int p = wid * 8 + 2 * (i0 + i) + h;
            int e = kk * 64 + p;
            wv[i] = paramw[e];
            ushort4 uo = paramo[e];
            __builtin_memcpy(&g[i][0], xb16 + ((int)uo.x << 9) + (lan << 4), 16);
            __builtin_memcpy(&g[i][1], xb16 + ((int)uo.y << 9) + (lan << 4), 16);
            __builtin_memcpy(&g[i][2], xb16 + ((int)uo.z << 9) + (lan << 4), 16);
            __builtin_memcpy(&g[i][3], xb16 + ((int)uo.w << 9) + (lan << 4), 16);
        }
    };

    auto pack_half = [&](int buf, int i0, uint4 (&g)[2][4], uint4 (&wv)[2]) {
        char* tb = (char*)&tile[buf][0];
#pragma unroll
        for (int i = 0; i < 2; ++i) {
            int p = wid * 8 + 2 * (i0 + i) + h;
            half2v c00[4], c01[4], c10[4], c11[4], w00, w01, w10, w11;
            __builtin_memcpy(&c00, &g[i][0], 16);
            __builtin_memcpy(&c01, &g[i][1], 16);
            __builtin_memcpy(&c10, &g[i][2], 16);
            __builtin_memcpy(&c11, &g[i][3], 16);
            __builtin_memcpy(&w00, &wv[i].x, 4);
            __builtin_memcpy(&w01, &wv[i].y, 4);
            __builtin_memcpy(&w10, &wv[i].z, 4);
            __builtin_memcpy(&w11, &wv[i].w, 4);
            uint4 outv;
            unsigned* op = (unsigned*)&outv;
#pragma unroll
            for (int j = 0; j < 4; ++j) {
                half2v r = c00[j] * w00;          // v_pk_mul_f16
                r = c01[j] * w01 + r;             // v_pk_fma_f16
                r = c10[j] * w10 + r;
                r = c11[j] * w11 + r;
                __builtin_memcpy(&op[j], &r, 4);
            }
            __builtin_memcpy(tb + lan * 1024 + ((p << 4) ^ (lan << 4)), &outv, 16);
        }
    };

    // prologue: build tile[0] for tap 0; preload uaA = tap 0, ks 0..7
    issue_half(0, 0, gA, wvA);
    pack_half(0, 0, gA, wvA);
    issue_half(0, 2, gB, wvB);
    pack_half(0, 2, gB, wvB);
#pragma unroll
    for (int ks = 0; ks < 8; ++ks) {
        int kul = ks * 2 + h;
        uaA[ks] = wb4[((size_t)wid * 288 + 0 * 32 + kul) * 32 + lan];
    }
    __syncthreads();

    for (int kk = 0; kk < 9; ++kk) {
        const int buf = kk & 1, nbuf = (kk + 1) & 1;

        // phase 1: issue uaB (this tap, ks 8..15) + next tap's gather half A
#pragma unroll
        for (int ks = 0; ks < 8; ++ks) {
            int kul = (ks + 8) * 2 + h;
            uaB[ks] = wb4[((size_t)wid * 288 + kk * 32 + kul) * 32 + lan];
        }
        if (kk < 8) issue_half(kk + 1, 0, gA, wvA);
        __builtin_amdgcn_sched_barrier(0);

        {   // phase 2: MFMA ks 0..7 on uaA -- already in registers, no wait
            const char* tb = (const char*)&tile[buf][0];
#pragma unroll
            for (int ks = 0; ks < 8; ++ks) {
                int kul = ks * 2 + h;
                uint4 ub0, ub1;
                __builtin_memcpy(&ub0, tb + kul * 1024 + ((lan << 4) ^ (kul << 4)), 16);
                __builtin_memcpy(&ub1, tb + kul * 1024 + (((32 + lan) << 4) ^ (kul << 4)), 16);
                half8 a, b0, b1;
                __builtin_memcpy(&a, &uaA[ks], 16);
                __builtin_memcpy(&b0, &ub0, 16);
                __builtin_memcpy(&b1, &ub1, 16);
                acc0 = __builtin_amdgcn_mfma_f32_32x32x16_f16(a, b0, acc0, 0, 0, 0);
                acc1 = __builtin_amdgcn_mfma_f32_32x32x16_f16(a, b1, acc1, 0, 0, 0);
            }
        }
        __builtin_amdgcn_sched_barrier(0);

        // phase 3: issue uaA (next tap, ks 0..7) + consume gA + issue gB
        if (kk < 8) {
#pragma unroll
            for (int ks = 0; ks < 8; ++ks) {
                int kul = ks * 2 + h;
                uaA[ks] = wb4[((size_t)wid * 288 + (kk + 1) * 32 + kul) * 32 + lan];
            }
            pack_half(nbuf, 0, gA, wvA);     // waits gA; uaA stays in flight
            issue_half(kk + 1, 2, gB, wvB);
        }
        __builtin_amdgcn_sched_barrier(0);

        {   // phase 4: MFMA ks 8..15 on uaB (issued phase 1 -> covered)
            const char* tb = (const char*)&tile[buf][0];
#pragma unroll
            for (int ks = 0; ks < 8; ++ks) {
                int kul = (ks + 8) * 2 + h;
                uint4 ub0, ub1;
                __builtin_memcpy(&ub0, tb + kul * 1024 + ((lan << 4) ^ (kul << 4)), 16);
                __builtin_memcpy(&ub1, tb + kul * 1024 + (((32 + lan) << 4) ^ (kul << 4)), 16);
                half8 a, b0, b1;
                __builtin_memcpy(&a, &uaB[ks], 16);
                __builtin_memcpy(&b0, &ub0, 16);
                __builtin_memcpy(&b1, &ub1, 16);
                acc0 = __builtin_amdgcn_mfma_f32_32x32x16_f16(a, b0, acc0, 0, 0, 0);
                acc1 = __builtin_amdgcn_mfma_f32_32x32x16_f16(a, b1, acc1, 0, 0, 0);
            }
        }
        __builtin_amdgcn_sched_barrier(0);

        // phase 5: consume gB
        if (kk < 8) pack_half(nbuf, 2, gB, wvB);
        __syncthreads();
    }

    // epilogue: wave wid owns m-tile wid, 2 n-tiles (verbatim)
#pragma unroll
    for (int nt = 0; nt < 2; ++nt) {
#pragma unroll
        for (int r = 0; r < 16; ++r) {
            int o = wid * 32 + (r & 3) + 8 * (r >> 2) + 4 * h;
            int woo = nt * 32 + lan;
            float v = (nt == 0) ? acc0[r] : acc1[r];
            out[(((size_t)b * 256 + o) * 64 + ho) * 64 + woo] = v + biasl[o];
        }
    }
}

extern "C" void kernel_launch(void* const* d_in, const int* in_sizes, int n_in,
                              void* d_out, int out_size, void* d_ws, size_t ws_size,
                              hipStream_t stream) {
    const float* x      = (const float*)d_in[0];
    const float* weight = (const float*)d_in[1];
    const float* bias   = (const float*)d_in[2];
    const float* off_w  = (const float*)d_in[3];
    const float* off_b  = (const float*)d_in[4];
    const float* mask_w = (const float*)d_in[5];
    const float* mask_b = (const float*)d_in[6];
    float* out = (float*)d_out;

    float* ws_off = (float*)d_ws;                                      // 1,769,472 B
    unsigned short* ws_b  = (unsigned short*)((char*)d_ws + 1769472);  // 1,179,648 B
    unsigned short* ws_a2 = (unsigned short*)((char*)d_ws + 2949120);  //   147,456 B
    unsigned short* xt    = (unsigned short*)((char*)d_ws + 3096576);  // 8,388,608 B

    hipLaunchKernelGGL(weight_pack_kernel, dim3(100), dim3(256), 0, stream,
                       weight, off_w, mask_w, ws_b, ws_a2);
    hipLaunchKernelGGL(xpose_hwc_kernel, dim3(256), dim3(256), 0, stream,
                       x, xt);
    hipLaunchKernelGGL(offmask_mfma_kernel, dim3(256), dim3(512), 0, stream,
                       xt, ws_a2, off_b, mask_b, ws_off);
    hipLaunchKernelGGL(deform_gemm_kernel, dim3(256), dim3(512), 0, stream,
                       xt, ws_off, ws_b, bias, out);
}

// Round 14
// 123.154 us; speedup vs baseline: 1.2787x; 1.0067x over previous
//
#include <hip/hip_runtime.h>
#include <hip/hip_bf16.h>
#include <string.h>

// DeformableConv2d: B=4, C=256, O=256, H=W=64, K=3, pad=1, stride=1
// Round 24: RESUBMIT #2 of round 22 (broker failed twice more; r7 precedent:
//   identical error string resolved by unchanged resubmit).  Hang audit
//   clean: all barriers uniform, all loops fixed-trip, all indices bounded.
//   Pre-commit: if this fails again, next round submits known-good r21 to
//   bisect infra-vs-source.
// Round 22: fuse K2 into K3 (one structural change vs r21).
//   r21 post-mortem: ua double-buffer was a wash (-0.9us) -> K3 is at its
//   L2-BW/structural floor for this geometry; restructure. K2's block
//   mapping is IDENTICAL to K3's (row=(bid&7)*32+(bid>>3), 256x512) ->
//   fuse: phase A computes offsets/mask into LDS offrow[1728] (K2 verbatim,
//   sigmoid included), phase B preps params from offrow, phase C runs the
//   r21 pipeline. Removes one launch + inter-kernel drain + the ws_off
//   global round-trip. All arithmetic bit-identical -> absmax 0.00390625.
//   LDS: 101376-B arena reused (stage/red | tile+params) + offrow 6912 +
//   biasl 1024 = 109312 B, 1 block/CU (unchanged).
// K0, K1 byte-identical to rounds 18-21.
// Workspace: ws_b 1179648 | ws_a2 147456 | xt 8388608 = 9,715,712 B.

typedef __attribute__((ext_vector_type(8))) short short8;
typedef __attribute__((ext_vector_type(8))) _Float16 half8;
typedef __attribute__((ext_vector_type(2))) _Float16 half2v;
typedef __attribute__((ext_vector_type(16))) float floatx16;

__device__ __forceinline__ unsigned bfbits(float f) {
    unsigned u;
    __builtin_memcpy(&u, &f, 4);
    return (u + 0x7fffu + ((u >> 16) & 1u)) >> 16;   // RNE f32->bf16
}
__device__ __forceinline__ unsigned pack_bf16(float lo, float hi) {
    return bfbits(lo) | (bfbits(hi) << 16);
}
__device__ __forceinline__ unsigned pack_f16(float lo, float hi) {
    _Float16 a = (_Float16)lo, b = (_Float16)hi;
    unsigned short ua, ub;
    __builtin_memcpy(&ua, &a, 2);
    __builtin_memcpy(&ub, &b, 2);
    return (unsigned)ua | ((unsigned)ub << 16);
}

// async global->LDS DMA, 16 B per lane; lane l's data lands at lds + l*16.
__device__ __forceinline__ void gl_lds16(const void* g, void* l) {
    __builtin_amdgcn_global_load_lds(
        (const __attribute__((address_space(1))) unsigned int*)g,
        (__attribute__((address_space(3))) unsigned int*)l,
        16, 0, 0);
}

// ---------------------------------------------------------------------------
// K0: x (B,C,H,W) f32 -> xt (B,H,W,C) f16.  One block per (b, y) row.
// (verbatim rounds 12-23)
// ---------------------------------------------------------------------------
__global__ __launch_bounds__(256) void xpose_hwc_kernel(
    const float* __restrict__ x, unsigned short* __restrict__ xt)
{
    __shared__ float stage[256 * 65];
    const int bid = blockIdx.x;          // (b*64 + y)
    const int b = bid >> 6, y = bid & 63;
    const int tid = threadIdx.x;
    const float* src = x + (size_t)b * 256 * 4096 + y * 64;

#pragma unroll
    for (int i = 0; i < 16; ++i) {
        int idx = i * 256 + tid;         // 0..4095 = (c, xq)
        int c = idx >> 4, xq = idx & 15;
        float4 v = *(const float4*)&src[(size_t)c * 4096 + xq * 4];
        stage[c * 65 + xq * 4 + 0] = v.x;
        stage[c * 65 + xq * 4 + 1] = v.y;
        stage[c * 65 + xq * 4 + 2] = v.z;
        stage[c * 65 + xq * 4 + 3] = v.w;
    }
    __syncthreads();

    unsigned short* dst = xt + (size_t)bid * 16384;   // 64 px * 256 ch
#pragma unroll
    for (int i = 0; i < 32; ++i) {
        int c2 = (tid & 127) * 2;
        int xx = i * 2 + (tid >> 7);
        float f0 = stage[c2 * 65 + xx];
        float f1 = stage[(c2 + 1) * 65 + xx];
        *(unsigned*)&dst[xx * 256 + c2] = pack_f16(f0, f1);
    }
}

// ---------------------------------------------------------------------------
// K1: weight pack (verbatim rounds 18-23; ws_b and ws_a2 both f16).
// ---------------------------------------------------------------------------
__global__ __launch_bounds__(256) void weight_pack_kernel(
    const float* __restrict__ w, const float* __restrict__ off_w,
    const float* __restrict__ mask_w,
    unsigned short* __restrict__ ws_b, unsigned short* __restrict__ ws_a2)
{
    __shared__ float slab[32 * 289];
    const int bid = blockIdx.x;
    const int tid = threadIdx.x;

    if (bid < 64) {
        const int nt = bid >> 3, cb = bid & 7;
        const float* wbase = w + (size_t)nt * 32 * 2304 + cb * 288;
#pragma unroll
        for (int i = 0; i < 9; ++i) {
            int idx = i * 256 + tid;               // 0..2303
            int o = idx / 72, f4 = idx % 72;
            float4 v = *(const float4*)&wbase[(size_t)o * 2304 + f4 * 4];
            slab[o * 289 + f4 * 4 + 0] = v.x;
            slab[o * 289 + f4 * 4 + 1] = v.y;
            slab[o * 289 + f4 * 4 + 2] = v.z;
            slab[o * 289 + f4 * 4 + 3] = v.w;
        }
        __syncthreads();
#pragma unroll
        for (int pass = 0; pass < 5; ++pass) {
            int rid = pass * 8 + (tid >> 5);
            if (rid < 36) {
                int kk = rid >> 2, q = rid & 3;
                int no = tid & 31;
                unsigned pk[4];
#pragma unroll
                for (int i = 0; i < 4; ++i) {
                    float f0 = slab[no * 289 + (q * 8 + 2 * i) * 9 + kk];
                    float f1 = slab[no * 289 + (q * 8 + 2 * i + 1) * 9 + kk];
                    pk[i] = pack_f16(f0, f1);          // f16 for the f16 MFMA
                }
                size_t u = ((size_t)nt * 288 + kk * 32 + cb * 4 + q) * 32 + no;
                *(uint4*)&ws_b[u * 8] = make_uint4(pk[0], pk[1], pk[2], pk[3]);
            }
        }
    } else {
        int e = (bid - 64) * 256 + tid;       // 0..9215
        int lan = e & 31;                     // oc row
        int ku = e >> 5;                      // 0..287
        int kk = ku >> 5;
        int c0 = (ku & 31) * 8;
        int o = lan;
        float f[8];
#pragma unroll
        for (int j = 0; j < 8; ++j) {
            int c = c0 + j;
            float v = 0.f;
            if (o < 18)      v = off_w[((size_t)o * 256 + c) * 9 + kk];
            else if (o < 27) v = mask_w[((size_t)(o - 18) * 256 + c) * 9 + kk];
            f[j] = v;
        }
        unsigned pk[4];
#pragma unroll
        for (int i = 0; i < 4; ++i) pk[i] = pack_f16(f[2 * i], f[2 * i + 1]);
        *(uint4*)&ws_a2[(size_t)e * 8] = make_uint4(pk[0], pk[1], pk[2], pk[3]);
    }
}

// ---------------------------------------------------------------------------
// K23: fused offset/mask conv + deformable sampling + GEMM.
// 256 blocks x 512 threads / 8 waves.  Block = row (same mapping as before).
// Phase A = r21-K2 verbatim, offs land in LDS offrow[1728].
// Phase B = param prep from offrow.  Phase C = r21-K3 pipeline verbatim.
// LDS: 101376-B arena (stage/red | tile+paramw+paramo) + offrow + biasl.
// ---------------------------------------------------------------------------
__global__ __launch_bounds__(512, 2) void fused_deform_kernel(
    const unsigned short* __restrict__ xt,
    const unsigned short* __restrict__ ws_a2,
    const unsigned short* __restrict__ ws_b,
    const float* __restrict__ off_b, const float* __restrict__ mask_b,
    const float* __restrict__ bias, float* __restrict__ out)
{
    __shared__ __align__(16) char smem[101376];   // arena
    __shared__ float offrow[1728];
    __shared__ float biasl[256];

    const int bid = blockIdx.x;
    const int row = (bid & 7) * 32 + (bid >> 3);
    const int b = row >> 6, ho = row & 63;
    const int tid = threadIdx.x;
    const int l = tid & 63;
    const int wid = tid >> 6;          // 0..7
    const int lan = l & 31, h = l >> 5;

    if (tid < 256) biasl[tid] = bias[tid];

    // ================= Phase A: offset/mask conv (r21-K2 verbatim) ========
    {
        uint4* stage = (uint4*)smem;   // [r][p01 0..65][granule j 0..31]
        const int ntile = wid >> 2, kq = wid & 3;
        const char* xtb = (const char*)xt + (size_t)b * 64 * 32768;
        for (int r = 0; r < 3; ++r) {
            int y = ho - 1 + r;
            uint4* rowbase = &stage[r * 66 * 32];
            if (y >= 0 && y < 64) {
                const char* src = xtb + (size_t)y * 32768;
#pragma unroll
                for (int i = 0; i < 4; ++i) {
                    int g0 = 32 + (wid * 4 + i) * 64;
                    int g = g0 + l;
                    int p01 = g >> 5, j = g & 31;
                    int kul = j ^ (p01 & 7);
                    gl_lds16(src + ((size_t)(p01 - 1) * 32 + kul) * 16,
                             rowbase + g0);
                }
                if (tid < 64) {
                    int g = (tid < 32) ? tid : (2080 + (tid - 32));
                    rowbase[g] = make_uint4(0, 0, 0, 0);
                }
            } else {
                for (int g = tid; g < 2112; g += 512)
                    rowbase[g] = make_uint4(0, 0, 0, 0);
            }
        }
        __syncthreads();              // DMA drained; stage complete

        floatx16 acc;
#pragma unroll
        for (int r = 0; r < 16; ++r) acc[r] = 0.f;

        const uint4* a4 = (const uint4*)ws_a2;
        const int n = ntile * 32 + lan;
#pragma unroll
        for (int ky = 0; ky < 3; ++ky) {
#pragma unroll
            for (int kx = 0; kx < 3; ++kx) {
                int kk = ky * 3 + kx;
                int p01 = n + kx;
#pragma unroll
                for (int s4 = 0; s4 < 4; ++s4) {
                    int s = kq * 4 + s4;
                    int kul = s * 2 + h;
                    uint4 ua = a4[(size_t)(kk * 32 + kul) * 32 + lan];
                    uint4 ub = stage[(ky * 66 + p01) * 32 + (kul ^ (p01 & 7))];
                    half8 a, bb;
                    __builtin_memcpy(&a, &ua, 16);
                    __builtin_memcpy(&bb, &ub, 16);
                    acc = __builtin_amdgcn_mfma_f32_32x32x16_f16(a, bb, acc, 0, 0, 0);
                }
            }
        }
        __syncthreads();              // all waves done reading stage

        float* red = (float*)smem;    // 32 KiB, aliases stage (dead)
#pragma unroll
        for (int r = 0; r < 16; ++r) red[(wid * 64 + l) * 16 + r] = acc[r];
        __syncthreads();
        for (int idx = tid; idx < 27 * 64; idx += 512) {
            int oc = idx >> 6, wo = idx & 63;
            int nt2 = wo >> 5, nn = wo & 31;
            int h2 = (oc >> 2) & 1;
            int r = (oc & 3) | ((oc >> 3) << 2);
            int lane2 = nn + 32 * h2;
            float s = 0.f;
#pragma unroll
            for (int kq2 = 0; kq2 < 4; ++kq2)
                s += red[((nt2 * 4 + kq2) * 64 + lane2) * 16 + r];
            float v;
            if (oc < 18) {
                v = s + off_b[oc];
            } else {
                float t = s + mask_b[oc - 18];
                v = 1.f / (1.f + expf(-t));
            }
            offrow[idx] = v;          // was: ws_off[row*1728 + idx]
        }
    }
    __syncthreads();                  // offrow ready; red/stage reads done

    // ================= Phase B: param prep (reads offrow) ================
    uint4*   paramw = (uint4*)(smem + 65536);          //  9,216 B
    ushort4* paramo = (ushort4*)(smem + 65536 + 9216); //  4,608 B
    {
        for (int it = tid; it < 576; it += 512) {
            int kk = it >> 6, p = it & 63;
            float dy = offrow[(2 * kk) * 64 + p];
            float dx = offrow[(2 * kk + 1) * 64 + p];
            float mk = offrow[(18 + kk) * 64 + p];
            int ky = kk / 3, kx = kk - ky * 3;
            float py = (float)(ho - 1 + ky) + dy;
            float px = (float)(p - 1 + kx) + dx;
            float y0f = floorf(py), x0f = floorf(px);
            float wy1 = py - y0f, wx1 = px - x0f;
            float wy0 = 1.f - wy1, wx0 = 1.f - wx1;
            int y0 = (int)y0f, xi0 = (int)x0f;
            int y1 = y0 + 1, xi1 = xi0 + 1;
            float vy0 = (y0 >= 0 && y0 < 64) ? 1.f : 0.f;
            float vy1 = (y1 >= 0 && y1 < 64) ? 1.f : 0.f;
            float vx0 = (xi0 >= 0 && xi0 < 64) ? 1.f : 0.f;
            float vx1 = (xi1 >= 0 && xi1 < 64) ? 1.f : 0.f;
            float wr0 = wy0 * vy0 * mk, wr1 = wy1 * vy1 * mk;
            float wa = wx0 * vx0, wb2 = wx1 * vx1;
            int yc0 = min(max(y0, 0), 63), yc1 = min(max(y1, 0), 63);
            int xc0 = min(max(xi0, 0), 63), xc1 = min(max(xi1, 0), 63);
            float a00 = wr0 * wa, a01 = wr0 * wb2;
            float a10 = wr1 * wa, a11 = wr1 * wb2;
            paramw[it] = make_uint4(pack_f16(a00, a00), pack_f16(a01, a01),
                                    pack_f16(a10, a10), pack_f16(a11, a11));
            paramo[it] = make_ushort4((unsigned short)(yc0 * 64 + xc0),
                                      (unsigned short)(yc0 * 64 + xc1),
                                      (unsigned short)(yc1 * 64 + xc0),
                                      (unsigned short)(yc1 * 64 + xc1));
        }
    }
    __syncthreads();

    // ================= Phase C: deform sampling + GEMM (r21-K3) ==========
    const char* xb16 = (const char*)xt + ((size_t)b << 21);   // b * 2 MiB
    const uint4* wb4 = (const uint4*)ws_b;

    floatx16 acc0, acc1;
#pragma unroll
    for (int r = 0; r < 16; ++r) { acc0[r] = 0.f; acc1[r] = 0.f; }

    uint4 gA[2][4], gB[2][4];
    uint4 wvA[2], wvB[2];
    uint4 uaA[8], uaB[8];

    auto issue_half = [&](int kk, int i0, uint4 (&g)[2][4], uint4 (&wv)[2]) {
#pragma unroll
        for (int i = 0; i < 2; ++i) {
            int p = wid * 8 + 2 * (i0 + i) + h;
            int e = kk * 64 + p;
            wv[i] = paramw[e];
            ushort4 uo = paramo[e];
            __builtin_memcpy(&g[i][0], xb16 + ((int)uo.x << 9) + (lan << 4), 16);
            __builtin_memcpy(&g[i][1], xb16 + ((int)uo.y << 9) + (lan << 4), 16);
            __builtin_memcpy(&g[i][2], xb16 + ((int)uo.z << 9) + (lan << 4), 16);
            __builtin_memcpy(&g[i][3], xb16 + ((int)uo.w << 9) + (lan << 4), 16);
        }
    };

    auto pack_half = [&](int buf, int i0, uint4 (&g)[2][4], uint4 (&wv)[2]) {
        char* tb = smem + buf * 32768;
#pragma unroll
        for (int i = 0; i < 2; ++i) {
            int p = wid * 8 + 2 * (i0 + i) + h;
            half2v c00[4], c01[4], c10[4], c11[4], w00, w01, w10, w11;
            __builtin_memcpy(&c00, &g[i][0], 16);
            __builtin_memcpy(&c01, &g[i][1], 16);
            __builtin_memcpy(&c10, &g[i][2], 16);
            __builtin_memcpy(&c11, &g[i][3], 16);
            __builtin_memcpy(&w00, &wv[i].x, 4);
            __builtin_memcpy(&w01, &wv[i].y, 4);
            __builtin_memcpy(&w10, &wv[i].z, 4);
            __builtin_memcpy(&w11, &wv[i].w, 4);
            uint4 outv;
            unsigned* op = (unsigned*)&outv;
#pragma unroll
            for (int j = 0; j < 4; ++j) {
                half2v r = c00[j] * w00;          // v_pk_mul_f16
                r = c01[j] * w01 + r;             // v_pk_fma_f16
                r = c10[j] * w10 + r;
                r = c11[j] * w11 + r;
                __builtin_memcpy(&op[j], &r, 4);
            }
            __builtin_memcpy(tb + lan * 1024 + ((p << 4) ^ (lan << 4)), &outv, 16);
        }
    };

    // prologue: build tile[0] for tap 0; preload uaA = tap 0, ks 0..7
    issue_half(0, 0, gA, wvA);
    pack_half(0, 0, gA, wvA);
    issue_half(0, 2, gB, wvB);
    pack_half(0, 2, gB, wvB);
#pragma unroll
    for (int ks = 0; ks < 8; ++ks) {
        int kul = ks * 2 + h;
        uaA[ks] = wb4[((size_t)wid * 288 + 0 * 32 + kul) * 32 + lan];
    }
    __syncthreads();

    for (int kk = 0; kk < 9; ++kk) {
        const int buf = kk & 1, nbuf = (kk + 1) & 1;

        // phase 1: issue uaB (this tap, ks 8..15) + next tap's gather half A
#pragma unroll
        for (int ks = 0; ks < 8; ++ks) {
            int kul = (ks + 8) * 2 + h;
            uaB[ks] = wb4[((size_t)wid * 288 + kk * 32 + kul) * 32 + lan];
        }
        if (kk < 8) issue_half(kk + 1, 0, gA, wvA);
        __builtin_amdgcn_sched_barrier(0);

        {   // phase 2: MFMA ks 0..7 on uaA (already in registers)
            const char* tb = smem + buf * 32768;
#pragma unroll
            for (int ks = 0; ks < 8; ++ks) {
                int kul = ks * 2 + h;
                uint4 ub0, ub1;
                __builtin_memcpy(&ub0, tb + kul * 1024 + ((lan << 4) ^ (kul << 4)), 16);
                __builtin_memcpy(&ub1, tb + kul * 1024 + (((32 + lan) << 4) ^ (kul << 4)), 16);
                half8 a, b0, b1;
                __builtin_memcpy(&a, &uaA[ks], 16);
                __builtin_memcpy(&b0, &ub0, 16);
                __builtin_memcpy(&b1, &ub1, 16);
                acc0 = __builtin_amdgcn_mfma_f32_32x32x16_f16(a, b0, acc0, 0, 0, 0);
                acc1 = __builtin_amdgcn_mfma_f32_32x32x16_f16(a, b1, acc1, 0, 0, 0);
            }
        }
        __builtin_amdgcn_sched_barrier(0);

        // phase 3: issue uaA (next tap, ks 0..7) + consume gA + issue gB
        if (kk < 8) {
#pragma unroll
            for (int ks = 0; ks < 8; ++ks) {
                int kul = ks * 2 + h;
                uaA[ks] = wb4[((size_t)wid * 288 + (kk + 1) * 32 + kul) * 32 + lan];
            }
            pack_half(nbuf, 0, gA, wvA);
            issue_half(kk + 1, 2, gB, wvB);
        }
        __builtin_amdgcn_sched_barrier(0);

        {   // phase 4: MFMA ks 8..15 on uaB (issued phase 1 -> covered)
            const char* tb = smem + buf * 32768;
#pragma unroll
            for (int ks = 0; ks < 8; ++ks) {
                int kul = (ks + 8) * 2 + h;
                uint4 ub0, ub1;
                __builtin_memcpy(&ub0, tb + kul * 1024 + ((lan << 4) ^ (kul << 4)), 16);
                __builtin_memcpy(&ub1, tb + kul * 1024 + (((32 + lan) << 4) ^ (kul << 4)), 16);
                half8 a, b0, b1;
                __builtin_memcpy(&a, &uaB[ks], 16);
                __builtin_memcpy(&b0, &ub0, 16);
                __builtin_memcpy(&b1, &ub1, 16);
                acc0 = __builtin_amdgcn_mfma_f32_32x32x16_f16(a, b0, acc0, 0, 0, 0);
                acc1 = __builtin_amdgcn_mfma_f32_32x32x16_f16(a, b1, acc1, 0, 0, 0);
            }
        }
        __builtin_amdgcn_sched_barrier(0);

        // phase 5: consume gB
        if (kk < 8) pack_half(nbuf, 2, gB, wvB);
        __syncthreads();
    }

    // epilogue: wave wid owns m-tile wid, 2 n-tiles (verbatim)
#pragma unroll
    for (int nt = 0; nt < 2; ++nt) {
#pragma unroll
        for (int r = 0; r < 16; ++r) {
            int o = wid * 32 + (r & 3) + 8 * (r >> 2) + 4 * h;
            int woo = nt * 32 + lan;
            float v = (nt == 0) ? acc0[r] : acc1[r];
            out[(((size_t)b * 256 + o) * 64 + ho) * 64 + woo] = v + biasl[o];
        }
    }
}

extern "C" void kernel_launch(void* const* d_in, const int* in_sizes, int n_in,
                              void* d_out, int out_size, void* d_ws, size_t ws_size,
                              hipStream_t stream) {
    const float* x      = (const float*)d_in[0];
    const float* weight = (const float*)d_in[1];
    const float* bias   = (const float*)d_in[2];
    const float* off_w  = (const float*)d_in[3];
    const float* off_b  = (const float*)d_in[4];
    const float* mask_w = (const float*)d_in[5];
    const float* mask_b = (const float*)d_in[6];
    float* out = (float*)d_out;

    unsigned short* ws_b  = (unsigned short*)d_ws;                     // 1,179,648 B
    unsigned short* ws_a2 = (unsigned short*)((char*)d_ws + 1179648);  //   147,456 B
    unsigned short* xt    = (unsigned short*)((char*)d_ws + 1327104);  // 8,388,608 B

    hipLaunchKernelGGL(weight_pack_kernel, dim3(100), dim3(256), 0, stream,
                       weight, off_w, mask_w, ws_b, ws_a2);
    hipLaunchKernelGGL(xpose_hwc_kernel, dim3(256), dim3(256), 0, stream,
                       x, xt);
    hipLaunchKernelGGL(fused_deform_kernel, dim3(256), dim3(512), 0, stream,
                       xt, ws_a2, ws_b, off_b, mask_b, bias, out);
}

// Round 15
// 122.056 us; speedup vs baseline: 1.2902x; 1.0090x over previous
//
#include <hip/hip_runtime.h>
#include <hip/hip_bf16.h>
#include <string.h>

// DeformableConv2d: B=4, C=256, O=256, H=W=64, K=3, pad=1, stride=1
// Round 25: merge K0+K1 into one prep_kernel (one change vs r22/r24).
//   r24 post-mortem: fusion landed correct (absmax bit-identical) but only
//   -0.8us -> inter-kernel drain was mostly hidden. Budget now: ~46us fixed
//   harness fill (256MiB poison, uncontrollable) + fused ~44 (50% L2-BW:
//   2.3MB/block at ~56B/cyc/CU = 41k cyc of 81k) + K0 ~7 + K1 ~3 + graph
//   ~20. All structural levers on the fused kernel are tested: occupancy
//   (r11 null, r16<r20), prefetch depth (r21 null), traffic cuts (net-neg
//   or accuracy-risky). Last safe lever: merge the two independent prep
//   kernels (both 256 thr) into one launch, grid 356, branch on blockIdx.
//   Bodies verbatim -> absmax stays 0.00390625.
// fused_deform_kernel byte-identical to rounds 22-24.
// Workspace: ws_b 1179648 | ws_a2 147456 | xt 8388608 = 9,715,712 B.

typedef __attribute__((ext_vector_type(8))) short short8;
typedef __attribute__((ext_vector_type(8))) _Float16 half8;
typedef __attribute__((ext_vector_type(2))) _Float16 half2v;
typedef __attribute__((ext_vector_type(16))) float floatx16;

__device__ __forceinline__ unsigned bfbits(float f) {
    unsigned u;
    __builtin_memcpy(&u, &f, 4);
    return (u + 0x7fffu + ((u >> 16) & 1u)) >> 16;   // RNE f32->bf16
}
__device__ __forceinline__ unsigned pack_bf16(float lo, float hi) {
    return bfbits(lo) | (bfbits(hi) << 16);
}
__device__ __forceinline__ unsigned pack_f16(float lo, float hi) {
    _Float16 a = (_Float16)lo, b = (_Float16)hi;
    unsigned short ua, ub;
    __builtin_memcpy(&ua, &a, 2);
    __builtin_memcpy(&ub, &b, 2);
    return (unsigned)ua | ((unsigned)ub << 16);
}

// async global->LDS DMA, 16 B per lane; lane l's data lands at lds + l*16.
__device__ __forceinline__ void gl_lds16(const void* g, void* l) {
    __builtin_amdgcn_global_load_lds(
        (const __attribute__((address_space(1))) unsigned int*)g,
        (__attribute__((address_space(3))) unsigned int*)l,
        16, 0, 0);
}

// ---------------------------------------------------------------------------
// prep_kernel: blocks 0..255 = K0 xpose (x f32 BCHW -> xt f16 BHWC);
//              blocks 256..355 = K1 weight pack.  Bodies verbatim r18-r24.
// LDS: shared 66,560-B arena (xpose stage 66,560 B; weight slab 36,992 B).
// ---------------------------------------------------------------------------
__global__ __launch_bounds__(256) void prep_kernel(
    const float* __restrict__ x, const float* __restrict__ w,
    const float* __restrict__ off_w, const float* __restrict__ mask_w,
    unsigned short* __restrict__ xt,
    unsigned short* __restrict__ ws_b, unsigned short* __restrict__ ws_a2)
{
    __shared__ float arena[256 * 65];     // 66,560 B
    const int tid = threadIdx.x;

    if (blockIdx.x < 256) {
        // ---------------- K0: xpose (verbatim) ----------------
        float* stage = arena;
        const int bid = blockIdx.x;          // (b*64 + y)
        const int b = bid >> 6, y = bid & 63;
        const float* src = x + (size_t)b * 256 * 4096 + y * 64;

#pragma unroll
        for (int i = 0; i < 16; ++i) {
            int idx = i * 256 + tid;         // 0..4095 = (c, xq)
            int c = idx >> 4, xq = idx & 15;
            float4 v = *(const float4*)&src[(size_t)c * 4096 + xq * 4];
            stage[c * 65 + xq * 4 + 0] = v.x;
            stage[c * 65 + xq * 4 + 1] = v.y;
            stage[c * 65 + xq * 4 + 2] = v.z;
            stage[c * 65 + xq * 4 + 3] = v.w;
        }
        __syncthreads();

        unsigned short* dst = xt + (size_t)bid * 16384;   // 64 px * 256 ch
#pragma unroll
        for (int i = 0; i < 32; ++i) {
            int c2 = (tid & 127) * 2;
            int xx = i * 2 + (tid >> 7);
            float f0 = stage[c2 * 65 + xx];
            float f1 = stage[(c2 + 1) * 65 + xx];
            *(unsigned*)&dst[xx * 256 + c2] = pack_f16(f0, f1);
        }
    } else {
        // ---------------- K1: weight pack (verbatim) ----------------
        float* slab = arena;                 // 32*289 floats = 36,992 B
        const int bid = blockIdx.x - 256;    // 0..99

        if (bid < 64) {
            const int nt = bid >> 3, cb = bid & 7;
            const float* wbase = w + (size_t)nt * 32 * 2304 + cb * 288;
#pragma unroll
            for (int i = 0; i < 9; ++i) {
                int idx = i * 256 + tid;               // 0..2303
                int o = idx / 72, f4 = idx % 72;
                float4 v = *(const float4*)&wbase[(size_t)o * 2304 + f4 * 4];
                slab[o * 289 + f4 * 4 + 0] = v.x;
                slab[o * 289 + f4 * 4 + 1] = v.y;
                slab[o * 289 + f4 * 4 + 2] = v.z;
                slab[o * 289 + f4 * 4 + 3] = v.w;
            }
            __syncthreads();
#pragma unroll
            for (int pass = 0; pass < 5; ++pass) {
                int rid = pass * 8 + (tid >> 5);
                if (rid < 36) {
                    int kk = rid >> 2, q = rid & 3;
                    int no = tid & 31;
                    unsigned pk[4];
#pragma unroll
                    for (int i = 0; i < 4; ++i) {
                        float f0 = slab[no * 289 + (q * 8 + 2 * i) * 9 + kk];
                        float f1 = slab[no * 289 + (q * 8 + 2 * i + 1) * 9 + kk];
                        pk[i] = pack_f16(f0, f1);      // f16 for the f16 MFMA
                    }
                    size_t u = ((size_t)nt * 288 + kk * 32 + cb * 4 + q) * 32 + no;
                    *(uint4*)&ws_b[u * 8] = make_uint4(pk[0], pk[1], pk[2], pk[3]);
                }
            }
        } else {
            int e = (bid - 64) * 256 + tid;       // 0..9215
            int lan = e & 31;                     // oc row
            int ku = e >> 5;                      // 0..287
            int kk = ku >> 5;
            int c0 = (ku & 31) * 8;
            int o = lan;
            float f[8];
#pragma unroll
            for (int j = 0; j < 8; ++j) {
                int c = c0 + j;
                float v = 0.f;
                if (o < 18)      v = off_w[((size_t)o * 256 + c) * 9 + kk];
                else if (o < 27) v = mask_w[((size_t)(o - 18) * 256 + c) * 9 + kk];
                f[j] = v;
            }
            unsigned pk[4];
#pragma unroll
            for (int i = 0; i < 4; ++i) pk[i] = pack_f16(f[2 * i], f[2 * i + 1]);
            *(uint4*)&ws_a2[(size_t)e * 8] = make_uint4(pk[0], pk[1], pk[2], pk[3]);
        }
    }
}

// ---------------------------------------------------------------------------
// fused_deform_kernel (verbatim rounds 22-24).
// 256 blocks x 512 threads / 8 waves.  Phase A = offset/mask conv ->
// offrow (LDS); Phase B = param prep; Phase C = pipelined sampling + GEMM.
// LDS: 101376-B arena + offrow 6912 + biasl 1024 = 109,312 B.
// ---------------------------------------------------------------------------
__global__ __launch_bounds__(512, 2) void fused_deform_kernel(
    const unsigned short* __restrict__ xt,
    const unsigned short* __restrict__ ws_a2,
    const unsigned short* __restrict__ ws_b,
    const float* __restrict__ off_b, const float* __restrict__ mask_b,
    const float* __restrict__ bias, float* __restrict__ out)
{
    __shared__ __align__(16) char smem[101376];   // arena
    __shared__ float offrow[1728];
    __shared__ float biasl[256];

    const int bid = blockIdx.x;
    const int row = (bid & 7) * 32 + (bid >> 3);
    const int b = row >> 6, ho = row & 63;
    const int tid = threadIdx.x;
    const int l = tid & 63;
    const int wid = tid >> 6;          // 0..7
    const int lan = l & 31, h = l >> 5;

    if (tid < 256) biasl[tid] = bias[tid];

    // ================= Phase A: offset/mask conv ========
    {
        uint4* stage = (uint4*)smem;   // [r][p01 0..65][granule j 0..31]
        const int ntile = wid >> 2, kq = wid & 3;
        const char* xtb = (const char*)xt + (size_t)b * 64 * 32768;
        for (int r = 0; r < 3; ++r) {
            int y = ho - 1 + r;
            uint4* rowbase = &stage[r * 66 * 32];
            if (y >= 0 && y < 64) {
                const char* src = xtb + (size_t)y * 32768;
#pragma unroll
                for (int i = 0; i < 4; ++i) {
                    int g0 = 32 + (wid * 4 + i) * 64;
                    int g = g0 + l;
                    int p01 = g >> 5, j = g & 31;
                    int kul = j ^ (p01 & 7);
                    gl_lds16(src + ((size_t)(p01 - 1) * 32 + kul) * 16,
                             rowbase + g0);
                }
                if (tid < 64) {
                    int g = (tid < 32) ? tid : (2080 + (tid - 32));
                    rowbase[g] = make_uint4(0, 0, 0, 0);
                }
            } else {
                for (int g = tid; g < 2112; g += 512)
                    rowbase[g] = make_uint4(0, 0, 0, 0);
            }
        }
        __syncthreads();              // DMA drained; stage complete

        floatx16 acc;
#pragma unroll
        for (int r = 0; r < 16; ++r) acc[r] = 0.f;

        const uint4* a4 = (const uint4*)ws_a2;
        const int n = ntile * 32 + lan;
#pragma unroll
        for (int ky = 0; ky < 3; ++ky) {
#pragma unroll
            for (int kx = 0; kx < 3; ++kx) {
                int kk = ky * 3 + kx;
                int p01 = n + kx;
#pragma unroll
                for (int s4 = 0; s4 < 4; ++s4) {
                    int s = kq * 4 + s4;
                    int kul = s * 2 + h;
                    uint4 ua = a4[(size_t)(kk * 32 + kul) * 32 + lan];
                    uint4 ub = stage[(ky * 66 + p01) * 32 + (kul ^ (p01 & 7))];
                    half8 a, bb;
                    __builtin_memcpy(&a, &ua, 16);
                    __builtin_memcpy(&bb, &ub, 16);
                    acc = __builtin_amdgcn_mfma_f32_32x32x16_f16(a, bb, acc, 0, 0, 0);
                }
            }
        }
        __syncthreads();              // all waves done reading stage

        float* red = (float*)smem;    // 32 KiB, aliases stage (dead)
#pragma unroll
        for (int r = 0; r < 16; ++r) red[(wid * 64 + l) * 16 + r] = acc[r];
        __syncthreads();
        for (int idx = tid; idx < 27 * 64; idx += 512) {
            int oc = idx >> 6, wo = idx & 63;
            int nt2 = wo >> 5, nn = wo & 31;
            int h2 = (oc >> 2) & 1;
            int r = (oc & 3) | ((oc >> 3) << 2);
            int lane2 = nn + 32 * h2;
            float s = 0.f;
#pragma unroll
            for (int kq2 = 0; kq2 < 4; ++kq2)
                s += red[((nt2 * 4 + kq2) * 64 + lane2) * 16 + r];
            float v;
            if (oc < 18) {
                v = s + off_b[oc];
            } else {
                float t = s + mask_b[oc - 18];
                v = 1.f / (1.f + expf(-t));
            }
            offrow[idx] = v;
        }
    }
    __syncthreads();                  // offrow ready; red/stage reads done

    // ================= Phase B: param prep (reads offrow) ================
    uint4*   paramw = (uint4*)(smem + 65536);          //  9,216 B
    ushort4* paramo = (ushort4*)(smem + 65536 + 9216); //  4,608 B
    {
        for (int it = tid; it < 576; it += 512) {
            int kk = it >> 6, p = it & 63;
            float dy = offrow[(2 * kk) * 64 + p];
            float dx = offrow[(2 * kk + 1) * 64 + p];
            float mk = offrow[(18 + kk) * 64 + p];
            int ky = kk / 3, kx = kk - ky * 3;
            float py = (float)(ho - 1 + ky) + dy;
            float px = (float)(p - 1 + kx) + dx;
            float y0f = floorf(py), x0f = floorf(px);
            float wy1 = py - y0f, wx1 = px - x0f;
            float wy0 = 1.f - wy1, wx0 = 1.f - wx1;
            int y0 = (int)y0f, xi0 = (int)x0f;
            int y1 = y0 + 1, xi1 = xi0 + 1;
            float vy0 = (y0 >= 0 && y0 < 64) ? 1.f : 0.f;
            float vy1 = (y1 >= 0 && y1 < 64) ? 1.f : 0.f;
            float vx0 = (xi0 >= 0 && xi0 < 64) ? 1.f : 0.f;
            float vx1 = (xi1 >= 0 && xi1 < 64) ? 1.f : 0.f;
            float wr0 = wy0 * vy0 * mk, wr1 = wy1 * vy1 * mk;
            float wa = wx0 * vx0, wb2 = wx1 * vx1;
            int yc0 = min(max(y0, 0), 63), yc1 = min(max(y1, 0), 63);
            int xc0 = min(max(xi0, 0), 63), xc1 = min(max(xi1, 0), 63);
            float a00 = wr0 * wa, a01 = wr0 * wb2;
            float a10 = wr1 * wa, a11 = wr1 * wb2;
            paramw[it] = make_uint4(pack_f16(a00, a00), pack_f16(a01, a01),
                                    pack_f16(a10, a10), pack_f16(a11, a11));
            paramo[it] = make_ushort4((unsigned short)(yc0 * 64 + xc0),
                                      (unsigned short)(yc0 * 64 + xc1),
                                      (unsigned short)(yc1 * 64 + xc0),
                                      (unsigned short)(yc1 * 64 + xc1));
        }
    }
    __syncthreads();

    // ================= Phase C: deform sampling + GEMM ==========
    const char* xb16 = (const char*)xt + ((size_t)b << 21);   // b * 2 MiB
    const uint4* wb4 = (const uint4*)ws_b;

    floatx16 acc0, acc1;
#pragma unroll
    for (int r = 0; r < 16; ++r) { acc0[r] = 0.f; acc1[r] = 0.f; }

    uint4 gA[2][4], gB[2][4];
    uint4 wvA[2], wvB[2];
    uint4 uaA[8], uaB[8];

    auto issue_half = [&](int kk, int i0, uint4 (&g)[2][4], uint4 (&wv)[2]) {
#pragma unroll
        for (int i = 0; i < 2; ++i) {
            int p = wid * 8 + 2 * (i0 + i) + h;
            int e = kk * 64 + p;
            wv[i] = paramw[e];
            ushort4 uo = paramo[e];
            __builtin_memcpy(&g[i][0], xb16 + ((int)uo.x << 9) + (lan << 4), 16);
            __builtin_memcpy(&g[i][1], xb16 + ((int)uo.y << 9) + (lan << 4), 16);
            __builtin_memcpy(&g[i][2], xb16 + ((int)uo.z << 9) + (lan << 4), 16);
            __builtin_memcpy(&g[i][3], xb16 + ((int)uo.w << 9) + (lan << 4), 16);
        }
    };

    auto pack_half = [&](int buf, int i0, uint4 (&g)[2][4], uint4 (&wv)[2]) {
        char* tb = smem + buf * 32768;
#pragma unroll
        for (int i = 0; i < 2; ++i) {
            int p = wid * 8 + 2 * (i0 + i) + h;
            half2v c00[4], c01[4], c10[4], c11[4], w00, w01, w10, w11;
            __builtin_memcpy(&c00, &g[i][0], 16);
            __builtin_memcpy(&c01, &g[i][1], 16);
            __builtin_memcpy(&c10, &g[i][2], 16);
            __builtin_memcpy(&c11, &g[i][3], 16);
            __builtin_memcpy(&w00, &wv[i].x, 4);
            __builtin_memcpy(&w01, &wv[i].y, 4);
            __builtin_memcpy(&w10, &wv[i].z, 4);
            __builtin_memcpy(&w11, &wv[i].w, 4);
            uint4 outv;
            unsigned* op = (unsigned*)&outv;
#pragma unroll
            for (int j = 0; j < 4; ++j) {
                half2v r = c00[j] * w00;          // v_pk_mul_f16
                r = c01[j] * w01 + r;             // v_pk_fma_f16
                r = c10[j] * w10 + r;
                r = c11[j] * w11 + r;
                __builtin_memcpy(&op[j], &r, 4);
            }
            __builtin_memcpy(tb + lan * 1024 + ((p << 4) ^ (lan << 4)), &outv, 16);
        }
    };

    // prologue: build tile[0] for tap 0; preload uaA = tap 0, ks 0..7
    issue_half(0, 0, gA, wvA);
    pack_half(0, 0, gA, wvA);
    issue_half(0, 2, gB, wvB);
    pack_half(0, 2, gB, wvB);
#pragma unroll
    for (int ks = 0; ks < 8; ++ks) {
        int kul = ks * 2 + h;
        uaA[ks] = wb4[((size_t)wid * 288 + 0 * 32 + kul) * 32 + lan];
    }
    __syncthreads();

    for (int kk = 0; kk < 9; ++kk) {
        const int buf = kk & 1, nbuf = (kk + 1) & 1;

        // phase 1: issue uaB (this tap, ks 8..15) + next tap's gather half A
#pragma unroll
        for (int ks = 0; ks < 8; ++ks) {
            int kul = (ks + 8) * 2 + h;
            uaB[ks] = wb4[((size_t)wid * 288 + kk * 32 + kul) * 32 + lan];
        }
        if (kk < 8) issue_half(kk + 1, 0, gA, wvA);
        __builtin_amdgcn_sched_barrier(0);

        {   // phase 2: MFMA ks 0..7 on uaA (already in registers)
            const char* tb = smem + buf * 32768;
#pragma unroll
            for (int ks = 0; ks < 8; ++ks) {
                int kul = ks * 2 + h;
                uint4 ub0, ub1;
                __builtin_memcpy(&ub0, tb + kul * 1024 + ((lan << 4) ^ (kul << 4)), 16);
                __builtin_memcpy(&ub1, tb + kul * 1024 + (((32 + lan) << 4) ^ (kul << 4)), 16);
                half8 a, b0, b1;
                __builtin_memcpy(&a, &uaA[ks], 16);
                __builtin_memcpy(&b0, &ub0, 16);
                __builtin_memcpy(&b1, &ub1, 16);
                acc0 = __builtin_amdgcn_mfma_f32_32x32x16_f16(a, b0, acc0, 0, 0, 0);
                acc1 = __builtin_amdgcn_mfma_f32_32x32x16_f16(a, b1, acc1, 0, 0, 0);
            }
        }
        __builtin_amdgcn_sched_barrier(0);

        // phase 3: issue uaA (next tap, ks 0..7) + consume gA + issue gB
        if (kk < 8) {
#pragma unroll
            for (int ks = 0; ks < 8; ++ks) {
                int kul = ks * 2 + h;
                uaA[ks] = wb4[((size_t)wid * 288 + (kk + 1) * 32 + kul) * 32 + lan];
            }
            pack_half(nbuf, 0, gA, wvA);
            issue_half(kk + 1, 2, gB, wvB);
        }
        __builtin_amdgcn_sched_barrier(0);

        {   // phase 4: MFMA ks 8..15 on uaB (issued phase 1 -> covered)
            const char* tb = smem + buf * 32768;
#pragma unroll
            for (int ks = 0; ks < 8; ++ks) {
                int kul = (ks + 8) * 2 + h;
                uint4 ub0, ub1;
                __builtin_memcpy(&ub0, tb + kul * 1024 + ((lan << 4) ^ (kul << 4)), 16);
                __builtin_memcpy(&ub1, tb + kul * 1024 + (((32 + lan) << 4) ^ (kul << 4)), 16);
                half8 a, b0, b1;
                __builtin_memcpy(&a, &uaB[ks], 16);
                __builtin_memcpy(&b0, &ub0, 16);
                __builtin_memcpy(&b1, &ub1, 16);
                acc0 = __builtin_amdgcn_mfma_f32_32x32x16_f16(a, b0, acc0, 0, 0, 0);
                acc1 = __builtin_amdgcn_mfma_f32_32x32x16_f16(a, b1, acc1, 0, 0, 0);
            }
        }
        __builtin_amdgcn_sched_barrier(0);

        // phase 5: consume gB
        if (kk < 8) pack_half(nbuf, 2, gB, wvB);
        __syncthreads();
    }

    // epilogue: wave wid owns m-tile wid, 2 n-tiles (verbatim)
#pragma unroll
    for (int nt = 0; nt < 2; ++nt) {
#pragma unroll
        for (int r = 0; r < 16; ++r) {
            int o = wid * 32 + (r & 3) + 8 * (r >> 2) + 4 * h;
            int woo = nt * 32 + lan;
            float v = (nt == 0) ? acc0[r] : acc1[r];
            out[(((size_t)b * 256 + o) * 64 + ho) * 64 + woo] = v + biasl[o];
        }
    }
}

extern "C" void kernel_launch(void* const* d_in, const int* in_sizes, int n_in,
                              void* d_out, int out_size, void* d_ws, size_t ws_size,
                              hipStream_t stream) {
    const float* x      = (const float*)d_in[0];
    const float* weight = (const float*)d_in[1];
    const float* bias   = (const float*)d_in[2];
    const float* off_w  = (const float*)d_in[3];
    const float* off_b  = (const float*)d_in[4];
    const float* mask_w = (const float*)d_in[5];
    const float* mask_b = (const float*)d_in[6];
    float* out = (float*)d_out;

    unsigned short* ws_b  = (unsigned short*)d_ws;                     // 1,179,648 B
    unsigned short* ws_a2 = (unsigned short*)((char*)d_ws + 1179648);  //   147,456 B
    unsigned short* xt    = (unsigned short*)((char*)d_ws + 1327104);  // 8,388,608 B

    hipLaunchKernelGGL(prep_kernel, dim3(356), dim3(256), 0, stream,
                       x, weight, off_w, mask_w, xt, ws_b, ws_a2);
    hipLaunchKernelGGL(fused_deform_kernel, dim3(256), dim3(512), 0, stream,
                       xt, ws_a2, ws_b, off_b, mask_b, bias, out);
}

// Round 16
// 121.177 us; speedup vs baseline: 1.2995x; 1.0073x over previous
//
#include <hip/hip_runtime.h>
#include <hip/hip_bf16.h>
#include <string.h>

// DeformableConv2d: B=4, C=256, O=256, H=W=64, K=3, pad=1, stride=1
// Round 26: Phase-A reduction bank-conflict fix (one change vs r25).
//   r25 post-mortem: fused kernel finally profiled -> SQ_LDS_BANK_CONFLICT
//   = 1.32M. Arithmetic locates it: red[(wid*64+l)*16+r] has bank =
//   (16l+r)%32 -> 64 lanes on 2 banks = 32-way conflict on 16 writes +
//   reads per thread (16w x 8waves x 256blk x ~30cyc ~= 1.2M, matches).
//   Fix: stride 16 -> 17 (coprime with 32 -> conflict-free), write+read.
//   red = 512*17*4 = 34,816 B, fits arena. Pure layout change ->
//   absmax stays 0.00390625 bit-exactly.
// prep_kernel and all other code byte-identical to round 25.
// Workspace: ws_b 1179648 | ws_a2 147456 | xt 8388608 = 9,715,712 B.

typedef __attribute__((ext_vector_type(8))) short short8;
typedef __attribute__((ext_vector_type(8))) _Float16 half8;
typedef __attribute__((ext_vector_type(2))) _Float16 half2v;
typedef __attribute__((ext_vector_type(16))) float floatx16;

__device__ __forceinline__ unsigned bfbits(float f) {
    unsigned u;
    __builtin_memcpy(&u, &f, 4);
    return (u + 0x7fffu + ((u >> 16) & 1u)) >> 16;   // RNE f32->bf16
}
__device__ __forceinline__ unsigned pack_bf16(float lo, float hi) {
    return bfbits(lo) | (bfbits(hi) << 16);
}
__device__ __forceinline__ unsigned pack_f16(float lo, float hi) {
    _Float16 a = (_Float16)lo, b = (_Float16)hi;
    unsigned short ua, ub;
    __builtin_memcpy(&ua, &a, 2);
    __builtin_memcpy(&ub, &b, 2);
    return (unsigned)ua | ((unsigned)ub << 16);
}

// async global->LDS DMA, 16 B per lane; lane l's data lands at lds + l*16.
__device__ __forceinline__ void gl_lds16(const void* g, void* l) {
    __builtin_amdgcn_global_load_lds(
        (const __attribute__((address_space(1))) unsigned int*)g,
        (__attribute__((address_space(3))) unsigned int*)l,
        16, 0, 0);
}

// ---------------------------------------------------------------------------
// prep_kernel: blocks 0..255 = K0 xpose (x f32 BCHW -> xt f16 BHWC);
//              blocks 256..355 = K1 weight pack.  (verbatim round 25)
// ---------------------------------------------------------------------------
__global__ __launch_bounds__(256) void prep_kernel(
    const float* __restrict__ x, const float* __restrict__ w,
    const float* __restrict__ off_w, const float* __restrict__ mask_w,
    unsigned short* __restrict__ xt,
    unsigned short* __restrict__ ws_b, unsigned short* __restrict__ ws_a2)
{
    __shared__ float arena[256 * 65];     // 66,560 B
    const int tid = threadIdx.x;

    if (blockIdx.x < 256) {
        // ---------------- K0: xpose (verbatim) ----------------
        float* stage = arena;
        const int bid = blockIdx.x;          // (b*64 + y)
        const int b = bid >> 6, y = bid & 63;
        const float* src = x + (size_t)b * 256 * 4096 + y * 64;

#pragma unroll
        for (int i = 0; i < 16; ++i) {
            int idx = i * 256 + tid;         // 0..4095 = (c, xq)
            int c = idx >> 4, xq = idx & 15;
            float4 v = *(const float4*)&src[(size_t)c * 4096 + xq * 4];
            stage[c * 65 + xq * 4 + 0] = v.x;
            stage[c * 65 + xq * 4 + 1] = v.y;
            stage[c * 65 + xq * 4 + 2] = v.z;
            stage[c * 65 + xq * 4 + 3] = v.w;
        }
        __syncthreads();

        unsigned short* dst = xt + (size_t)bid * 16384;   // 64 px * 256 ch
#pragma unroll
        for (int i = 0; i < 32; ++i) {
            int c2 = (tid & 127) * 2;
            int xx = i * 2 + (tid >> 7);
            float f0 = stage[c2 * 65 + xx];
            float f1 = stage[(c2 + 1) * 65 + xx];
            *(unsigned*)&dst[xx * 256 + c2] = pack_f16(f0, f1);
        }
    } else {
        // ---------------- K1: weight pack (verbatim) ----------------
        float* slab = arena;                 // 32*289 floats = 36,992 B
        const int bid = blockIdx.x - 256;    // 0..99

        if (bid < 64) {
            const int nt = bid >> 3, cb = bid & 7;
            const float* wbase = w + (size_t)nt * 32 * 2304 + cb * 288;
#pragma unroll
            for (int i = 0; i < 9; ++i) {
                int idx = i * 256 + tid;               // 0..2303
                int o = idx / 72, f4 = idx % 72;
                float4 v = *(const float4*)&wbase[(size_t)o * 2304 + f4 * 4];
                slab[o * 289 + f4 * 4 + 0] = v.x;
                slab[o * 289 + f4 * 4 + 1] = v.y;
                slab[o * 289 + f4 * 4 + 2] = v.z;
                slab[o * 289 + f4 * 4 + 3] = v.w;
            }
            __syncthreads();
#pragma unroll
            for (int pass = 0; pass < 5; ++pass) {
                int rid = pass * 8 + (tid >> 5);
                if (rid < 36) {
                    int kk = rid >> 2, q = rid & 3;
                    int no = tid & 31;
                    unsigned pk[4];
#pragma unroll
                    for (int i = 0; i < 4; ++i) {
                        float f0 = slab[no * 289 + (q * 8 + 2 * i) * 9 + kk];
                        float f1 = slab[no * 289 + (q * 8 + 2 * i + 1) * 9 + kk];
                        pk[i] = pack_f16(f0, f1);      // f16 for the f16 MFMA
                    }
                    size_t u = ((size_t)nt * 288 + kk * 32 + cb * 4 + q) * 32 + no;
                    *(uint4*)&ws_b[u * 8] = make_uint4(pk[0], pk[1], pk[2], pk[3]);
                }
            }
        } else {
            int e = (bid - 64) * 256 + tid;       // 0..9215
            int lan = e & 31;                     // oc row
            int ku = e >> 5;                      // 0..287
            int kk = ku >> 5;
            int c0 = (ku & 31) * 8;
            int o = lan;
            float f[8];
#pragma unroll
            for (int j = 0; j < 8; ++j) {
                int c = c0 + j;
                float v = 0.f;
                if (o < 18)      v = off_w[((size_t)o * 256 + c) * 9 + kk];
                else if (o < 27) v = mask_w[((size_t)(o - 18) * 256 + c) * 9 + kk];
                f[j] = v;
            }
            unsigned pk[4];
#pragma unroll
            for (int i = 0; i < 4; ++i) pk[i] = pack_f16(f[2 * i], f[2 * i + 1]);
            *(uint4*)&ws_a2[(size_t)e * 8] = make_uint4(pk[0], pk[1], pk[2], pk[3]);
        }
    }
}

// ---------------------------------------------------------------------------
// fused_deform_kernel: Phase A offset/mask conv -> offrow (LDS); Phase B
// param prep; Phase C pipelined sampling + GEMM.  (r25 + red stride 17)
// LDS: 101376-B arena + offrow 6912 + biasl 1024 = 109,312 B.
// ---------------------------------------------------------------------------
__global__ __launch_bounds__(512, 2) void fused_deform_kernel(
    const unsigned short* __restrict__ xt,
    const unsigned short* __restrict__ ws_a2,
    const unsigned short* __restrict__ ws_b,
    const float* __restrict__ off_b, const float* __restrict__ mask_b,
    const float* __restrict__ bias, float* __restrict__ out)
{
    __shared__ __align__(16) char smem[101376];   // arena
    __shared__ float offrow[1728];
    __shared__ float biasl[256];

    const int bid = blockIdx.x;
    const int row = (bid & 7) * 32 + (bid >> 3);
    const int b = row >> 6, ho = row & 63;
    const int tid = threadIdx.x;
    const int l = tid & 63;
    const int wid = tid >> 6;          // 0..7
    const int lan = l & 31, h = l >> 5;

    if (tid < 256) biasl[tid] = bias[tid];

    // ================= Phase A: offset/mask conv ========
    {
        uint4* stage = (uint4*)smem;   // [r][p01 0..65][granule j 0..31]
        const int ntile = wid >> 2, kq = wid & 3;
        const char* xtb = (const char*)xt + (size_t)b * 64 * 32768;
        for (int r = 0; r < 3; ++r) {
            int y = ho - 1 + r;
            uint4* rowbase = &stage[r * 66 * 32];
            if (y >= 0 && y < 64) {
                const char* src = xtb + (size_t)y * 32768;
#pragma unroll
                for (int i = 0; i < 4; ++i) {
                    int g0 = 32 + (wid * 4 + i) * 64;
                    int g = g0 + l;
                    int p01 = g >> 5, j = g & 31;
                    int kul = j ^ (p01 & 7);
                    gl_lds16(src + ((size_t)(p01 - 1) * 32 + kul) * 16,
                             rowbase + g0);
                }
                if (tid < 64) {
                    int g = (tid < 32) ? tid : (2080 + (tid - 32));
                    rowbase[g] = make_uint4(0, 0, 0, 0);
                }
            } else {
                for (int g = tid; g < 2112; g += 512)
                    rowbase[g] = make_uint4(0, 0, 0, 0);
            }
        }
        __syncthreads();              // DMA drained; stage complete

        floatx16 acc;
#pragma unroll
        for (int r = 0; r < 16; ++r) acc[r] = 0.f;

        const uint4* a4 = (const uint4*)ws_a2;
        const int n = ntile * 32 + lan;
#pragma unroll
        for (int ky = 0; ky < 3; ++ky) {
#pragma unroll
            for (int kx = 0; kx < 3; ++kx) {
                int kk = ky * 3 + kx;
                int p01 = n + kx;
#pragma unroll
                for (int s4 = 0; s4 < 4; ++s4) {
                    int s = kq * 4 + s4;
                    int kul = s * 2 + h;
                    uint4 ua = a4[(size_t)(kk * 32 + kul) * 32 + lan];
                    uint4 ub = stage[(ky * 66 + p01) * 32 + (kul ^ (p01 & 7))];
                    half8 a, bb;
                    __builtin_memcpy(&a, &ua, 16);
                    __builtin_memcpy(&bb, &ub, 16);
                    acc = __builtin_amdgcn_mfma_f32_32x32x16_f16(a, bb, acc, 0, 0, 0);
                }
            }
        }
        __syncthreads();              // all waves done reading stage

        // cross-wave reduction, stride 17 (conflict-free: gcd(17,32)=1)
        float* red = (float*)smem;    // 512*17*4 = 34,816 B, aliases stage
#pragma unroll
        for (int r = 0; r < 16; ++r) red[(wid * 64 + l) * 17 + r] = acc[r];
        __syncthreads();
        for (int idx = tid; idx < 27 * 64; idx += 512) {
            int oc = idx >> 6, wo = idx & 63;
            int nt2 = wo >> 5, nn = wo & 31;
            int h2 = (oc >> 2) & 1;
            int r = (oc & 3) | ((oc >> 3) << 2);
            int lane2 = nn + 32 * h2;
            float s = 0.f;
#pragma unroll
            for (int kq2 = 0; kq2 < 4; ++kq2)
                s += red[((nt2 * 4 + kq2) * 64 + lane2) * 17 + r];
            float v;
            if (oc < 18) {
                v = s + off_b[oc];
            } else {
                float t = s + mask_b[oc - 18];
                v = 1.f / (1.f + expf(-t));
            }
            offrow[idx] = v;
        }
    }
    __syncthreads();                  // offrow ready; red/stage reads done

    // ================= Phase B: param prep (reads offrow) ================
    uint4*   paramw = (uint4*)(smem + 65536);          //  9,216 B
    ushort4* paramo = (ushort4*)(smem + 65536 + 9216); //  4,608 B
    {
        for (int it = tid; it < 576; it += 512) {
            int kk = it >> 6, p = it & 63;
            float dy = offrow[(2 * kk) * 64 + p];
            float dx = offrow[(2 * kk + 1) * 64 + p];
            float mk = offrow[(18 + kk) * 64 + p];
            int ky = kk / 3, kx = kk - ky * 3;
            float py = (float)(ho - 1 + ky) + dy;
            float px = (float)(p - 1 + kx) + dx;
            float y0f = floorf(py), x0f = floorf(px);
            float wy1 = py - y0f, wx1 = px - x0f;
            float wy0 = 1.f - wy1, wx0 = 1.f - wx1;
            int y0 = (int)y0f, xi0 = (int)x0f;
            int y1 = y0 + 1, xi1 = xi0 + 1;
            float vy0 = (y0 >= 0 && y0 < 64) ? 1.f : 0.f;
            float vy1 = (y1 >= 0 && y1 < 64) ? 1.f : 0.f;
            float vx0 = (xi0 >= 0 && xi0 < 64) ? 1.f : 0.f;
            float vx1 = (xi1 >= 0 && xi1 < 64) ? 1.f : 0.f;
            float wr0 = wy0 * vy0 * mk, wr1 = wy1 * vy1 * mk;
            float wa = wx0 * vx0, wb2 = wx1 * vx1;
            int yc0 = min(max(y0, 0), 63), yc1 = min(max(y1, 0), 63);
            int xc0 = min(max(xi0, 0), 63), xc1 = min(max(xi1, 0), 63);
            float a00 = wr0 * wa, a01 = wr0 * wb2;
            float a10 = wr1 * wa, a11 = wr1 * wb2;
            paramw[it] = make_uint4(pack_f16(a00, a00), pack_f16(a01, a01),
                                    pack_f16(a10, a10), pack_f16(a11, a11));
            paramo[it] = make_ushort4((unsigned short)(yc0 * 64 + xc0),
                                      (unsigned short)(yc0 * 64 + xc1),
                                      (unsigned short)(yc1 * 64 + xc0),
                                      (unsigned short)(yc1 * 64 + xc1));
        }
    }
    __syncthreads();

    // ================= Phase C: deform sampling + GEMM ==========
    const char* xb16 = (const char*)xt + ((size_t)b << 21);   // b * 2 MiB
    const uint4* wb4 = (const uint4*)ws_b;

    floatx16 acc0, acc1;
#pragma unroll
    for (int r = 0; r < 16; ++r) { acc0[r] = 0.f; acc1[r] = 0.f; }

    uint4 gA[2][4], gB[2][4];
    uint4 wvA[2], wvB[2];
    uint4 uaA[8], uaB[8];

    auto issue_half = [&](int kk, int i0, uint4 (&g)[2][4], uint4 (&wv)[2]) {
#pragma unroll
        for (int i = 0; i < 2; ++i) {
            int p = wid * 8 + 2 * (i0 + i) + h;
            int e = kk * 64 + p;
            wv[i] = paramw[e];
            ushort4 uo = paramo[e];
            __builtin_memcpy(&g[i][0], xb16 + ((int)uo.x << 9) + (lan << 4), 16);
            __builtin_memcpy(&g[i][1], xb16 + ((int)uo.y << 9) + (lan << 4), 16);
            __builtin_memcpy(&g[i][2], xb16 + ((int)uo.z << 9) + (lan << 4), 16);
            __builtin_memcpy(&g[i][3], xb16 + ((int)uo.w << 9) + (lan << 4), 16);
        }
    };

    auto pack_half = [&](int buf, int i0, uint4 (&g)[2][4], uint4 (&wv)[2]) {
        char* tb = smem + buf * 32768;
#pragma unroll
        for (int i = 0; i < 2; ++i) {
            int p = wid * 8 + 2 * (i0 + i) + h;
            half2v c00[4], c01[4], c10[4], c11[4], w00, w01, w10, w11;
            __builtin_memcpy(&c00, &g[i][0], 16);
            __builtin_memcpy(&c01, &g[i][1], 16);
            __builtin_memcpy(&c10, &g[i][2], 16);
            __builtin_memcpy(&c11, &g[i][3], 16);
            __builtin_memcpy(&w00, &wv[i].x, 4);
            __builtin_memcpy(&w01, &wv[i].y, 4);
            __builtin_memcpy(&w10, &wv[i].z, 4);
            __builtin_memcpy(&w11, &wv[i].w, 4);
            uint4 outv;
            unsigned* op = (unsigned*)&outv;
#pragma unroll
            for (int j = 0; j < 4; ++j) {
                half2v r = c00[j] * w00;          // v_pk_mul_f16
                r = c01[j] * w01 + r;             // v_pk_fma_f16
                r = c10[j] * w10 + r;
                r = c11[j] * w11 + r;
                __builtin_memcpy(&op[j], &r, 4);
            }
            __builtin_memcpy(tb + lan * 1024 + ((p << 4) ^ (lan << 4)), &outv, 16);
        }
    };

    // prologue: build tile[0] for tap 0; preload uaA = tap 0, ks 0..7
    issue_half(0, 0, gA, wvA);
    pack_half(0, 0, gA, wvA);
    issue_half(0, 2, gB, wvB);
    pack_half(0, 2, gB, wvB);
#pragma unroll
    for (int ks = 0; ks < 8; ++ks) {
        int kul = ks * 2 + h;
        uaA[ks] = wb4[((size_t)wid * 288 + 0 * 32 + kul) * 32 + lan];
    }
    __syncthreads();

    for (int kk = 0; kk < 9; ++kk) {
        const int buf = kk & 1, nbuf = (kk + 1) & 1;

        // phase 1: issue uaB (this tap, ks 8..15) + next tap's gather half A
#pragma unroll
        for (int ks = 0; ks < 8; ++ks) {
            int kul = (ks + 8) * 2 + h;
            uaB[ks] = wb4[((size_t)wid * 288 + kk * 32 + kul) * 32 + lan];
        }
        if (kk < 8) issue_half(kk + 1, 0, gA, wvA);
        __builtin_amdgcn_sched_barrier(0);

        {   // phase 2: MFMA ks 0..7 on uaA (already in registers)
            const char* tb = smem + buf * 32768;
#pragma unroll
            for (int ks = 0; ks < 8; ++ks) {
                int kul = ks * 2 + h;
                uint4 ub0, ub1;
                __builtin_memcpy(&ub0, tb + kul * 1024 + ((lan << 4) ^ (kul << 4)), 16);
                __builtin_memcpy(&ub1, tb + kul * 1024 + (((32 + lan) << 4) ^ (kul << 4)), 16);
                half8 a, b0, b1;
                __builtin_memcpy(&a, &uaA[ks], 16);
                __builtin_memcpy(&b0, &ub0, 16);
                __builtin_memcpy(&b1, &ub1, 16);
                acc0 = __builtin_amdgcn_mfma_f32_32x32x16_f16(a, b0, acc0, 0, 0, 0);
                acc1 = __builtin_amdgcn_mfma_f32_32x32x16_f16(a, b1, acc1, 0, 0, 0);
            }
        }
        __builtin_amdgcn_sched_barrier(0);

        // phase 3: issue uaA (next tap, ks 0..7) + consume gA + issue gB
        if (kk < 8) {
#pragma unroll
            for (int ks = 0; ks < 8; ++ks) {
                int kul = ks * 2 + h;
                uaA[ks] = wb4[((size_t)wid * 288 + (kk + 1) * 32 + kul) * 32 + lan];
            }
            pack_half(nbuf, 0, gA, wvA);
            issue_half(kk + 1, 2, gB, wvB);
        }
        __builtin_amdgcn_sched_barrier(0);

        {   // phase 4: MFMA ks 8..15 on uaB (issued phase 1 -> covered)
            const char* tb = smem + buf * 32768;
#pragma unroll
            for (int ks = 0; ks < 8; ++ks) {
                int kul = (ks + 8) * 2 + h;
                uint4 ub0, ub1;
                __builtin_memcpy(&ub0, tb + kul * 1024 + ((lan << 4) ^ (kul << 4)), 16);
                __builtin_memcpy(&ub1, tb + kul * 1024 + (((32 + lan) << 4) ^ (kul << 4)), 16);
                half8 a, b0, b1;
                __builtin_memcpy(&a, &uaB[ks], 16);
                __builtin_memcpy(&b0, &ub0, 16);
                __builtin_memcpy(&b1, &ub1, 16);
                acc0 = __builtin_amdgcn_mfma_f32_32x32x16_f16(a, b0, acc0, 0, 0, 0);
                acc1 = __builtin_amdgcn_mfma_f32_32x32x16_f16(a, b1, acc1, 0, 0, 0);
            }
        }
        __builtin_amdgcn_sched_barrier(0);

        // phase 5: consume gB
        if (kk < 8) pack_half(nbuf, 2, gB, wvB);
        __syncthreads();
    }

    // epilogue: wave wid owns m-tile wid, 2 n-tiles (verbatim)
#pragma unroll
    for (int nt = 0; nt < 2; ++nt) {
#pragma unroll
        for (int r = 0; r < 16; ++r) {
            int o = wid * 32 + (r & 3) + 8 * (r >> 2) + 4 * h;
            int woo = nt * 32 + lan;
            float v = (nt == 0) ? acc0[r] : acc1[r];
            out[(((size_t)b * 256 + o) * 64 + ho) * 64 + woo] = v + biasl[o];
        }
    }
}

extern "C" void kernel_launch(void* const* d_in, const int* in_sizes, int n_in,
                              void* d_out, int out_size, void* d_ws, size_t ws_size,
                              hipStream_t stream) {
    const float* x      = (const float*)d_in[0];
    const float* weight = (const float*)d_in[1];
    const float* bias   = (const float*)d_in[2];
    const float* off_w  = (const float*)d_in[3];
    const float* off_b  = (const float*)d_in[4];
    const float* mask_w = (const float*)d_in[5];
    const float* mask_b = (const float*)d_in[6];
    float* out = (float*)d_out;

    unsigned short* ws_b  = (unsigned short*)d_ws;                     // 1,179,648 B
    unsigned short* ws_a2 = (unsigned short*)((char*)d_ws + 1179648);  //   147,456 B
    unsigned short* xt    = (unsigned short*)((char*)d_ws + 1327104);  // 8,388,608 B

    hipLaunchKernelGGL(prep_kernel, dim3(356), dim3(256), 0, stream,
                       x, weight, off_w, mask_w, xt, ws_b, ws_a2);
    hipLaunchKernelGGL(fused_deform_kernel, dim3(256), dim3(512), 0, stream,
                       xt, ws_a2, ws_b, off_b, mask_b, bias, out);
}